// Round 2
// baseline (2826.843 us; speedup 1.0000x reference)
//
#include <hip/hip_runtime.h>

#define HH 4  // heads

// ============================ CSR build ============================
__global__ void hist_kernel(const int* __restrict__ dst, int* __restrict__ deg, int E) {
    int i = blockIdx.x * blockDim.x + threadIdx.x;
    if (i < E) atomicAdd(&deg[dst[i]], 1);
}

__global__ void scan_block(const int* __restrict__ deg, int* __restrict__ rs,
                           int* __restrict__ bsum, int n) {
    __shared__ int buf[1024];
    int i = blockIdx.x * 1024 + threadIdx.x;
    int v = (i < n) ? deg[i] : 0;
    buf[threadIdx.x] = v;
    __syncthreads();
    for (int off = 1; off < 1024; off <<= 1) {
        int t = (threadIdx.x >= off) ? buf[threadIdx.x - off] : 0;
        __syncthreads();
        buf[threadIdx.x] += t;
        __syncthreads();
    }
    if (i < n) rs[i + 1] = buf[threadIdx.x];  // inclusive scan into rs[i+1]
    if (threadIdx.x == 1023) bsum[blockIdx.x] = buf[1023];
}

__global__ void scan_top(int* bsum, int nb) {
    if (threadIdx.x == 0 && blockIdx.x == 0) {
        int acc = 0;
        for (int b = 0; b < nb; ++b) { int t = bsum[b]; bsum[b] = acc; acc += t; }
    }
}

__global__ void scan_add(int* __restrict__ rs, const int* __restrict__ bsum, int n) {
    int i = blockIdx.x * blockDim.x + threadIdx.x;
    if (i == 0) rs[0] = 0;
    if (i < n) rs[i + 1] += bsum[i >> 10];
}

__global__ void scatter_kernel(const int* __restrict__ src, const int* __restrict__ dst,
                               const int* __restrict__ rs, int* __restrict__ cur,
                               int* __restrict__ csrc, int E) {
    int i = blockIdx.x * blockDim.x + threadIdx.x;
    if (i >= E) return;
    int d = dst[i];
    int p = rs[d] + atomicAdd(&cur[d], 1);
    csrc[p] = src[i];
}

// ============================ GEMM: 4 rows/block, register tiled ============================
template <int KOUT, int TPB>
__global__ void gemm4(const float* __restrict__ x, const float* __restrict__ W,
                      float* __restrict__ f, int relu_in, int n) {
    constexpr int RPB = 4;
    constexpr int CPT = KOUT / TPB;
    __shared__ float xs[RPB][128];
    const int row0 = blockIdx.x * RPB;
    for (int i = threadIdx.x; i < RPB * 128; i += TPB) {
        int r = row0 + (i >> 7);
        float v = (r < n) ? x[(size_t)r * 128 + (i & 127)] : 0.0f;
        if (relu_in) v = fmaxf(v, 0.0f);
        xs[i >> 7][i & 127] = v;
    }
    __syncthreads();
    float acc[RPB][CPT];
#pragma unroll
    for (int r = 0; r < RPB; ++r)
#pragma unroll
        for (int j = 0; j < CPT; ++j) acc[r][j] = 0.0f;
    const int col = threadIdx.x;
    for (int k = 0; k < 128; k += 4) {
        float4 xv[RPB];
#pragma unroll
        for (int r = 0; r < RPB; ++r) xv[r] = *reinterpret_cast<const float4*>(&xs[r][k]);
#pragma unroll
        for (int kk = 0; kk < 4; ++kk) {
            float w[CPT];
#pragma unroll
            for (int j = 0; j < CPT; ++j) w[j] = W[(size_t)(k + kk) * KOUT + col + j * TPB];
#pragma unroll
            for (int r = 0; r < RPB; ++r) {
                float xr = ((const float*)&xv[r])[kk];
#pragma unroll
                for (int j = 0; j < CPT; ++j) acc[r][j] = fmaf(xr, w[j], acc[r][j]);
            }
        }
    }
#pragma unroll
    for (int r = 0; r < RPB; ++r) {
        int row = row0 + r;
        if (row < n) {
#pragma unroll
            for (int j = 0; j < CPT; ++j) f[(size_t)row * KOUT + col + j * TPB] = acc[r][j];
        }
    }
}

// ============================ el/er ============================
template <int C>
__global__ void elr_kernel(const float* __restrict__ f, const float* __restrict__ al,
                           const float* __restrict__ ar, float* __restrict__ el,
                           float* __restrict__ er, int nh) {
    int idx = blockIdx.x * blockDim.x + threadIdx.x;
    if (idx >= nh) return;
    int node = idx / HH, h = idx % HH;
    const float* fp = f + (size_t)node * (HH * C) + h * C;
    float sl = 0.0f, sr = 0.0f;
    for (int c = 0; c < C; ++c) {
        float v = fp[c];
        sl = fmaf(v, al[h * C + c], sl);
        sr = fmaf(v, ar[h * C + c], sr);
    }
    el[idx] = sl;
    er[idx] = sr;
}

// ============================ fused softmax + aggregation (one wave per dst node) ============================
template <int K>
__global__ void aggr_csr(const int* __restrict__ rs, const int* __restrict__ csrc,
                         const float* __restrict__ el, const float* __restrict__ er,
                         const float* __restrict__ f, float* __restrict__ out, int n) {
    constexpr int CPT = K / 64;            // cols per lane (8 for 512, 2 for 128)
    const int wid = (blockIdx.x * blockDim.x + threadIdx.x) >> 6;  // one wave per node
    if (wid >= n) return;
    const int lane = threadIdx.x & 63;
    const int h = lane >> 4;               // 16-lane group per head (cols lane*CPT all in head lane/16)
    const int d = wid;
    const int e0 = rs[d], e1 = rs[d + 1];
    const float erd = er[d * HH + h];

    // phase A: per-head max over incoming edges (edges parallel across the 16-lane group)
    float m = -1e30f;
    for (int e = e0 + (lane & 15); e < e1; e += 16) {
        int s = csrc[e];
        float v = el[s * HH + h] + erd;
        v = (v >= 0.0f) ? v : 0.2f * v;
        m = fmaxf(m, v);
    }
#pragma unroll
    for (int off = 1; off < 16; off <<= 1) m = fmaxf(m, __shfl_xor(m, off));

    // phase B: z = sum exp(e - m)
    float z = 0.0f;
    for (int e = e0 + (lane & 15); e < e1; e += 16) {
        int s = csrc[e];
        float v = el[s * HH + h] + erd;
        v = (v >= 0.0f) ? v : 0.2f * v;
        z += __expf(v - m);
    }
#pragma unroll
    for (int off = 1; off < 16; off <<= 1) z += __shfl_xor(z, off);
    const float rz = (z > 0.0f) ? 1.0f / z : 0.0f;

    // phase C: out[d, :] = sum_e alpha * f[src, :]
    float acc[CPT];
#pragma unroll
    for (int j = 0; j < CPT; ++j) acc[j] = 0.0f;
    const int colbase = lane * CPT;
    for (int e = e0; e < e1; ++e) {
        int s = csrc[e];
        float v = el[s * HH + h] + erd;
        v = (v >= 0.0f) ? v : 0.2f * v;
        float alpha = __expf(v - m) * rz;
        const float* fp = f + (size_t)s * K + colbase;
        if constexpr (CPT == 8) {
            float4 a = *reinterpret_cast<const float4*>(fp);
            float4 b = *reinterpret_cast<const float4*>(fp + 4);
            acc[0] = fmaf(alpha, a.x, acc[0]);
            acc[1] = fmaf(alpha, a.y, acc[1]);
            acc[2] = fmaf(alpha, a.z, acc[2]);
            acc[3] = fmaf(alpha, a.w, acc[3]);
            acc[4] = fmaf(alpha, b.x, acc[4]);
            acc[5] = fmaf(alpha, b.y, acc[5]);
            acc[6] = fmaf(alpha, b.z, acc[6]);
            acc[7] = fmaf(alpha, b.w, acc[7]);
        } else {
            float2 a = *reinterpret_cast<const float2*>(fp);
            acc[0] = fmaf(alpha, a.x, acc[0]);
            acc[1] = fmaf(alpha, a.y, acc[1]);
        }
    }
#pragma unroll
    for (int j = 0; j < CPT; ++j) out[(size_t)d * K + colbase + j] = acc[j];
}

// ============================ global max pool (with relu) ============================
__global__ void pool_kernel(const float* __restrict__ o, unsigned* __restrict__ pooled, int n) {
    const int col = threadIdx.x;  // 512 threads
    float m = 0.0f;
    for (int r = blockIdx.x; r < n; r += gridDim.x) m = fmaxf(m, o[(size_t)r * 512 + col]);
    m = fmaxf(m, 0.0f);
    atomicMax(&pooled[col], __float_as_uint(m));  // nonneg: uint order == float order
}

// ============================ FC head + softmax ============================
__global__ void head_kernel(const float* __restrict__ pooled, const float* __restrict__ fcw,
                            const float* __restrict__ fcb, float* __restrict__ out) {
    __shared__ float logits[8];
    int t = threadIdx.x;
    if (t < 8) {
        float acc = fcb[t];
        for (int i = 0; i < 512; ++i) acc = fmaf(pooled[i], fcw[i * 8 + t], acc);
        logits[t] = acc;
    }
    __syncthreads();
    if (t == 0) {
        float mx = -1e30f;
        for (int j = 0; j < 8; ++j) mx = fmaxf(mx, logits[j]);
        float ex[8], s = 0.0f;
        for (int j = 0; j < 8; ++j) { ex[j] = expf(logits[j] - mx); s += ex[j]; }
        for (int j = 0; j < 8; ++j) out[j] = ex[j] / s;
    }
}

extern "C" void kernel_launch(void* const* d_in, const int* in_sizes, int n_in,
                              void* d_out, int out_size, void* d_ws, size_t ws_size,
                              hipStream_t stream) {
    const float* x0  = (const float*)d_in[0];
    const int*   src = (const int*)d_in[1];
    const int*   dst = (const int*)d_in[2];
    const float* W0  = (const float*)d_in[3];
    const float* al0 = (const float*)d_in[4];
    const float* ar0 = (const float*)d_in[5];
    const float* W1  = (const float*)d_in[6];
    const float* al1 = (const float*)d_in[7];
    const float* ar1 = (const float*)d_in[8];
    const float* W2  = (const float*)d_in[9];
    const float* al2 = (const float*)d_in[10];
    const float* ar2 = (const float*)d_in[11];
    const float* fcw = (const float*)d_in[12];
    const float* fcb = (const float*)d_in[13];
    float* outp = (float*)d_out;

    const int N = in_sizes[0] / 128;
    const int E = in_sizes[1];

    // -------- workspace layout --------
    float* F  = (float*)d_ws;                    // N*512
    float* OA = F + (size_t)N * 512;             // N*512
    float* OB = OA + (size_t)N * 512;            // N*128
    float* el = OB + (size_t)N * 128;            // N*4
    float* er = el + (size_t)N * HH;             // N*4
    float* pooled = er + (size_t)N * HH;         // 512
    int* rs   = (int*)(pooled + 512);            // N+1
    int* deg  = rs + (N + 1);                    // N
    int* cur  = deg + N;                         // N
    int* bsum = cur + N;                         // 64
    int* csrc = bsum + 64;                       // E

    // -------- CSR build (once; graph shared by all 3 layers) --------
    hipMemsetAsync(deg, 0, (size_t)2 * N * sizeof(int), stream);  // deg + cur
    hist_kernel<<<(E + 255) / 256, 256, 0, stream>>>(dst, deg, E);
    const int nb = (N + 1023) / 1024;
    scan_block<<<nb, 1024, 0, stream>>>(deg, rs, bsum, N);
    scan_top<<<1, 64, 0, stream>>>(bsum, nb);
    scan_add<<<(N + 255) / 256, 256, 0, stream>>>(rs, bsum, N);
    scatter_kernel<<<(E + 255) / 256, 256, 0, stream>>>(src, dst, rs, cur, csrc, E);

    const int nh = N * HH;
    auto run_layer = [&](const float* x, int relu_in, const float* W, const float* al,
                         const float* ar, int K, float* obuf) {
        if (K == 128) {
            gemm4<128, 128><<<(N + 3) / 4, 128, 0, stream>>>(x, W, F, relu_in, N);
            elr_kernel<32><<<(nh + 255) / 256, 256, 0, stream>>>(F, al, ar, el, er, nh);
            aggr_csr<128><<<(N + 3) / 4, 256, 0, stream>>>(rs, csrc, el, er, F, obuf, N);
        } else {
            gemm4<512, 256><<<(N + 3) / 4, 256, 0, stream>>>(x, W, F, relu_in, N);
            elr_kernel<128><<<(nh + 255) / 256, 256, 0, stream>>>(F, al, ar, el, er, nh);
            aggr_csr<512><<<(N + 3) / 4, 256, 0, stream>>>(rs, csrc, el, er, F, obuf, N);
        }
    };

    run_layer(x0, 0, W0, al0, ar0, 128, OA);   // layer 0 -> OA (N*128)
    run_layer(OA, 1, W1, al1, ar1, 128, OB);   // layer 1 -> OB (N*128)
    run_layer(OB, 1, W2, al2, ar2, 512, OA);   // layer 2 -> OA (N*512)

    hipMemsetAsync(pooled, 0, 512 * sizeof(float), stream);
    pool_kernel<<<256, 512, 0, stream>>>(OA, (unsigned*)pooled, N);
    head_kernel<<<1, 64, 0, stream>>>(pooled, fcw, fcb, outp);
}

// Round 3
// 614.703 us; speedup vs baseline: 4.5987x; 4.5987x over previous
//
#include <hip/hip_runtime.h>

#define HH 4  // heads

// ============================ CSR build ============================
__global__ void hist_kernel(const int* __restrict__ dst, int* __restrict__ deg, int E) {
    int i = blockIdx.x * blockDim.x + threadIdx.x;
    if (i < E) atomicAdd(&deg[dst[i]], 1);
}

__global__ void scan_block(const int* __restrict__ deg, int* __restrict__ rs,
                           int* __restrict__ bsum, int n) {
    __shared__ int buf[1024];
    int i = blockIdx.x * 1024 + threadIdx.x;
    int v = (i < n) ? deg[i] : 0;
    buf[threadIdx.x] = v;
    __syncthreads();
    for (int off = 1; off < 1024; off <<= 1) {
        int t = (threadIdx.x >= off) ? buf[threadIdx.x - off] : 0;
        __syncthreads();
        buf[threadIdx.x] += t;
        __syncthreads();
    }
    if (i < n) rs[i + 1] = buf[threadIdx.x];
    if (threadIdx.x == 1023) bsum[blockIdx.x] = buf[1023];
}

__global__ void scan_top(int* bsum, int nb) {
    if (threadIdx.x == 0 && blockIdx.x == 0) {
        int acc = 0;
        for (int b = 0; b < nb; ++b) { int t = bsum[b]; bsum[b] = acc; acc += t; }
    }
}

__global__ void scan_add(int* __restrict__ rs, const int* __restrict__ bsum, int n) {
    int i = blockIdx.x * blockDim.x + threadIdx.x;
    if (i == 0) rs[0] = 0;
    if (i < n) rs[i + 1] += bsum[i >> 10];
}

__global__ void scatter_kernel(const int* __restrict__ src, const int* __restrict__ dst,
                               const int* __restrict__ rs, int* __restrict__ cur,
                               int* __restrict__ csrc, int E) {
    int i = blockIdx.x * blockDim.x + threadIdx.x;
    if (i >= E) return;
    int d = dst[i];
    int p = rs[d] + atomicAdd(&cur[d], 1);
    csrc[p] = src[i];
}

// ============================ tiled GEMM: 64 rows x 128 cols per block ============================
// grid: ((n+63)/64, KOUT/128), block 256. k-tile 32, both operands in LDS.
template <int KOUT>
__global__ __launch_bounds__(256) void gemm_tiled(const float* __restrict__ x,
                                                  const float* __restrict__ W,
                                                  float* __restrict__ f, int relu_in, int n) {
    constexpr int BM = 64, BK = 32, BN = 128;
    __shared__ float xs[BM][BK + 1];   // +1 pad: trow groups land on distinct banks
    __shared__ float ws[BK][BN];       // stride 128 ≡ 0 mod 32; reads use 64-split, 2-way (free)
    const int row0 = blockIdx.x * BM;
    const int col0 = blockIdx.y * BN;
    const int tid = threadIdx.x;
    const int trow = tid >> 4;   // 0..15 -> 4 rows each
    const int tcol = tid & 15;   // 0..15 -> cols tcol*4 and 64+tcol*4

    float acc[4][8];
#pragma unroll
    for (int r = 0; r < 4; ++r)
#pragma unroll
        for (int j = 0; j < 8; ++j) acc[r][j] = 0.0f;

    for (int k0 = 0; k0 < 128; k0 += BK) {
        for (int i = tid; i < BM * BK; i += 256) {
            int r = i >> 5, kk = i & 31;
            int row = row0 + r;
            float v = (row < n) ? x[(size_t)row * 128 + k0 + kk] : 0.0f;
            if (relu_in) v = fmaxf(v, 0.0f);
            xs[r][kk] = v;
        }
        for (int i = tid; i < BK * BN; i += 256) {
            int kk = i >> 7, c = i & 127;
            ws[kk][c] = W[(size_t)(k0 + kk) * KOUT + col0 + c];
        }
        __syncthreads();
#pragma unroll 4
        for (int kk = 0; kk < BK; ++kk) {
            float4 w0 = *reinterpret_cast<const float4*>(&ws[kk][tcol * 4]);
            float4 w1 = *reinterpret_cast<const float4*>(&ws[kk][tcol * 4 + 64]);
            float xr[4];
#pragma unroll
            for (int r = 0; r < 4; ++r) xr[r] = xs[trow * 4 + r][kk];
#pragma unroll
            for (int r = 0; r < 4; ++r) {
                acc[r][0] = fmaf(xr[r], w0.x, acc[r][0]);
                acc[r][1] = fmaf(xr[r], w0.y, acc[r][1]);
                acc[r][2] = fmaf(xr[r], w0.z, acc[r][2]);
                acc[r][3] = fmaf(xr[r], w0.w, acc[r][3]);
                acc[r][4] = fmaf(xr[r], w1.x, acc[r][4]);
                acc[r][5] = fmaf(xr[r], w1.y, acc[r][5]);
                acc[r][6] = fmaf(xr[r], w1.z, acc[r][6]);
                acc[r][7] = fmaf(xr[r], w1.w, acc[r][7]);
            }
        }
        __syncthreads();
    }
#pragma unroll
    for (int r = 0; r < 4; ++r) {
        int row = row0 + trow * 4 + r;
        if (row < n) {
            float4 o0 = {acc[r][0], acc[r][1], acc[r][2], acc[r][3]};
            float4 o1 = {acc[r][4], acc[r][5], acc[r][6], acc[r][7]};
            *reinterpret_cast<float4*>(&f[(size_t)row * KOUT + col0 + tcol * 4]) = o0;
            *reinterpret_cast<float4*>(&f[(size_t)row * KOUT + col0 + tcol * 4 + 64]) = o1;
        }
    }
}

// ============================ el/er ============================
template <int C>
__global__ void elr_kernel(const float* __restrict__ f, const float* __restrict__ al,
                           const float* __restrict__ ar, float* __restrict__ el,
                           float* __restrict__ er, int nh) {
    int idx = blockIdx.x * blockDim.x + threadIdx.x;
    if (idx >= nh) return;
    int node = idx / HH, h = idx % HH;
    const float* fp = f + (size_t)node * (HH * C) + h * C;
    float sl = 0.0f, sr = 0.0f;
    for (int c = 0; c < C; ++c) {
        float v = fp[c];
        sl = fmaf(v, al[h * C + c], sl);
        sr = fmaf(v, ar[h * C + c], sr);
    }
    el[idx] = sl;
    er[idx] = sr;
}

// ============================ fused softmax + aggregation (one BLOCK per dst node) ============================
// 4 waves: softmax stats computed redundantly per wave; gather phase splits edges across waves.
template <int K>
__global__ __launch_bounds__(256) void aggr_csr(const int* __restrict__ rs,
                                                const int* __restrict__ csrc,
                                                const float* __restrict__ el,
                                                const float* __restrict__ er,
                                                const float* __restrict__ f,
                                                float* __restrict__ out, int n) {
    constexpr int CPT = K / 64;  // 8 for 512, 2 for 128
    __shared__ float part[4][K];
    const int d = blockIdx.x;
    const int tid = threadIdx.x;
    const int wave = tid >> 6, lane = tid & 63;
    const int h = lane >> 4;     // head of this lane's columns
    const int e0 = rs[d], e1 = rs[d + 1];
    const float erd = er[d * HH + h];

    // phase A: per-head max (edges parallel across each 16-lane group)
    float m = -1e30f;
    for (int e = e0 + (lane & 15); e < e1; e += 16) {
        float v = el[csrc[e] * HH + h] + erd;
        v = (v >= 0.0f) ? v : 0.2f * v;
        m = fmaxf(m, v);
    }
#pragma unroll
    for (int off = 1; off < 16; off <<= 1) m = fmaxf(m, __shfl_xor(m, off));

    // phase B: z
    float z = 0.0f;
    for (int e = e0 + (lane & 15); e < e1; e += 16) {
        float v = el[csrc[e] * HH + h] + erd;
        v = (v >= 0.0f) ? v : 0.2f * v;
        z += __expf(v - m);
    }
#pragma unroll
    for (int off = 1; off < 16; off <<= 1) z += __shfl_xor(z, off);
    const float rz = (z > 0.0f) ? 1.0f / z : 0.0f;

    // phase C: edges split across the 4 waves
    float acc[CPT];
#pragma unroll
    for (int j = 0; j < CPT; ++j) acc[j] = 0.0f;
    const int colbase = lane * CPT;
    for (int e = e0 + wave; e < e1; e += 4) {
        int s = csrc[e];
        float v = el[s * HH + h] + erd;
        v = (v >= 0.0f) ? v : 0.2f * v;
        float alpha = __expf(v - m) * rz;
        const float* fp = f + (size_t)s * K + colbase;
        if constexpr (CPT == 8) {
            float4 a = *reinterpret_cast<const float4*>(fp);
            float4 b = *reinterpret_cast<const float4*>(fp + 4);
            acc[0] = fmaf(alpha, a.x, acc[0]);
            acc[1] = fmaf(alpha, a.y, acc[1]);
            acc[2] = fmaf(alpha, a.z, acc[2]);
            acc[3] = fmaf(alpha, a.w, acc[3]);
            acc[4] = fmaf(alpha, b.x, acc[4]);
            acc[5] = fmaf(alpha, b.y, acc[5]);
            acc[6] = fmaf(alpha, b.z, acc[6]);
            acc[7] = fmaf(alpha, b.w, acc[7]);
        } else {
            float2 a = *reinterpret_cast<const float2*>(fp);
            acc[0] = fmaf(alpha, a.x, acc[0]);
            acc[1] = fmaf(alpha, a.y, acc[1]);
        }
    }
#pragma unroll
    for (int j = 0; j < CPT; ++j) part[wave][colbase + j] = acc[j];
    __syncthreads();
    for (int c = tid; c < K; c += 256)
        out[(size_t)d * K + c] = part[0][c] + part[1][c] + part[2][c] + part[3][c];
}

// ============================ global max pool (with relu) ============================
__global__ void pool_kernel(const float* __restrict__ o, unsigned* __restrict__ pooled, int n) {
    const int col = threadIdx.x;  // 512 threads
    float m = 0.0f;
    for (int r = blockIdx.x; r < n; r += gridDim.x) m = fmaxf(m, o[(size_t)r * 512 + col]);
    m = fmaxf(m, 0.0f);
    atomicMax(&pooled[col], __float_as_uint(m));  // nonneg: uint order == float order
}

// ============================ FC head + softmax ============================
__global__ void head_kernel(const float* __restrict__ pooled, const float* __restrict__ fcw,
                            const float* __restrict__ fcb, float* __restrict__ out) {
    __shared__ float logits[8];
    int t = threadIdx.x;
    if (t < 8) {
        float acc = fcb[t];
        for (int i = 0; i < 512; ++i) acc = fmaf(pooled[i], fcw[i * 8 + t], acc);
        logits[t] = acc;
    }
    __syncthreads();
    if (t == 0) {
        float mx = -1e30f;
        for (int j = 0; j < 8; ++j) mx = fmaxf(mx, logits[j]);
        float ex[8], s = 0.0f;
        for (int j = 0; j < 8; ++j) { ex[j] = expf(logits[j] - mx); s += ex[j]; }
        for (int j = 0; j < 8; ++j) out[j] = ex[j] / s;
    }
}

extern "C" void kernel_launch(void* const* d_in, const int* in_sizes, int n_in,
                              void* d_out, int out_size, void* d_ws, size_t ws_size,
                              hipStream_t stream) {
    const float* x0  = (const float*)d_in[0];
    const int*   src = (const int*)d_in[1];
    const int*   dst = (const int*)d_in[2];
    const float* W0  = (const float*)d_in[3];
    const float* al0 = (const float*)d_in[4];
    const float* ar0 = (const float*)d_in[5];
    const float* W1  = (const float*)d_in[6];
    const float* al1 = (const float*)d_in[7];
    const float* ar1 = (const float*)d_in[8];
    const float* W2  = (const float*)d_in[9];
    const float* al2 = (const float*)d_in[10];
    const float* ar2 = (const float*)d_in[11];
    const float* fcw = (const float*)d_in[12];
    const float* fcb = (const float*)d_in[13];
    float* outp = (float*)d_out;

    const int N = in_sizes[0] / 128;
    const int E = in_sizes[1];

    // -------- workspace layout --------
    float* F  = (float*)d_ws;                    // N*512
    float* OA = F + (size_t)N * 512;             // N*512
    float* OB = OA + (size_t)N * 512;            // N*128
    float* el = OB + (size_t)N * 128;            // N*4
    float* er = el + (size_t)N * HH;             // N*4
    float* pooled = er + (size_t)N * HH;         // 512
    int* rs   = (int*)(pooled + 512);            // N+1
    int* deg  = rs + (N + 1);                    // N
    int* cur  = deg + N;                         // N
    int* bsum = cur + N;                         // 64
    int* csrc = bsum + 64;                       // E

    // -------- CSR build (once; graph shared by all 3 layers) --------
    hipMemsetAsync(deg, 0, (size_t)2 * N * sizeof(int), stream);  // deg + cur
    hist_kernel<<<(E + 255) / 256, 256, 0, stream>>>(dst, deg, E);
    const int nb = (N + 1023) / 1024;
    scan_block<<<nb, 1024, 0, stream>>>(deg, rs, bsum, N);
    scan_top<<<1, 64, 0, stream>>>(bsum, nb);
    scan_add<<<(N + 255) / 256, 256, 0, stream>>>(rs, bsum, N);
    scatter_kernel<<<(E + 255) / 256, 256, 0, stream>>>(src, dst, rs, cur, csrc, E);

    const int nh = N * HH;
    const int rowTiles = (N + 63) / 64;
    auto run_layer = [&](const float* x, int relu_in, const float* W, const float* al,
                         const float* ar, int K, float* obuf) {
        if (K == 128) {
            gemm_tiled<128><<<dim3(rowTiles, 1), 256, 0, stream>>>(x, W, F, relu_in, N);
            elr_kernel<32><<<(nh + 255) / 256, 256, 0, stream>>>(F, al, ar, el, er, nh);
            aggr_csr<128><<<N, 256, 0, stream>>>(rs, csrc, el, er, F, obuf, N);
        } else {
            gemm_tiled<512><<<dim3(rowTiles, 4), 256, 0, stream>>>(x, W, F, relu_in, N);
            elr_kernel<128><<<(nh + 255) / 256, 256, 0, stream>>>(F, al, ar, el, er, nh);
            aggr_csr<512><<<N, 256, 0, stream>>>(rs, csrc, el, er, F, obuf, N);
        }
    };

    run_layer(x0, 0, W0, al0, ar0, 128, OA);   // layer 0 -> OA (N*128)
    run_layer(OA, 1, W1, al1, ar1, 128, OB);   // layer 1 -> OB (N*128)
    run_layer(OB, 1, W2, al2, ar2, 512, OA);   // layer 2 -> OA (N*512)

    hipMemsetAsync(pooled, 0, 512 * sizeof(float), stream);
    pool_kernel<<<256, 512, 0, stream>>>(OA, (unsigned*)pooled, N);
    head_kernel<<<1, 64, 0, stream>>>(pooled, fcw, fcb, outp);
}

// Round 4
// 441.668 us; speedup vs baseline: 6.4004x; 1.3918x over previous
//
#include <hip/hip_runtime.h>

#define HH 4  // heads

// ============================ CSR build ============================
__global__ void hist_kernel(const int* __restrict__ dst, int* __restrict__ deg, int E) {
    int i = blockIdx.x * blockDim.x + threadIdx.x;
    if (i < E) atomicAdd(&deg[dst[i]], 1);
}

__global__ void scan_block(const int* __restrict__ deg, int* __restrict__ rs,
                           int* __restrict__ bsum, int n) {
    __shared__ int buf[1024];
    int i = blockIdx.x * 1024 + threadIdx.x;
    int v = (i < n) ? deg[i] : 0;
    buf[threadIdx.x] = v;
    __syncthreads();
    for (int off = 1; off < 1024; off <<= 1) {
        int t = (threadIdx.x >= off) ? buf[threadIdx.x - off] : 0;
        __syncthreads();
        buf[threadIdx.x] += t;
        __syncthreads();
    }
    if (i < n) rs[i + 1] = buf[threadIdx.x];
    if (threadIdx.x == 1023) bsum[blockIdx.x] = buf[1023];
}

__global__ void scan_top(int* bsum, int nb) {
    if (threadIdx.x == 0 && blockIdx.x == 0) {
        int acc = 0;
        for (int b = 0; b < nb; ++b) { int t = bsum[b]; bsum[b] = acc; acc += t; }
    }
}

__global__ void scan_add(int* __restrict__ rs, const int* __restrict__ bsum, int n) {
    int i = blockIdx.x * blockDim.x + threadIdx.x;
    if (i == 0) rs[0] = 0;
    if (i < n) rs[i + 1] += bsum[i >> 10];
}

__global__ void scatter_kernel(const int* __restrict__ src, const int* __restrict__ dst,
                               const int* __restrict__ rs, int* __restrict__ cur,
                               int* __restrict__ csrc, int E) {
    int i = blockIdx.x * blockDim.x + threadIdx.x;
    if (i >= E) return;
    int d = dst[i];
    int p = rs[d] + atomicAdd(&cur[d], 1);
    csrc[p] = src[i];
}

// ============================ tiled GEMM: 64 rows x 128 cols per block ============================
template <int KOUT>
__global__ __launch_bounds__(256) void gemm_tiled(const float* __restrict__ x,
                                                  const float* __restrict__ W,
                                                  float* __restrict__ f, int relu_in, int n) {
    constexpr int BM = 64, BK = 32, BN = 128;
    __shared__ float xs[BM][BK + 1];
    __shared__ float ws[BK][BN];
    const int row0 = blockIdx.x * BM;
    const int col0 = blockIdx.y * BN;
    const int tid = threadIdx.x;
    const int trow = tid >> 4;
    const int tcol = tid & 15;

    float acc[4][8];
#pragma unroll
    for (int r = 0; r < 4; ++r)
#pragma unroll
        for (int j = 0; j < 8; ++j) acc[r][j] = 0.0f;

    for (int k0 = 0; k0 < 128; k0 += BK) {
        for (int i = tid; i < BM * BK; i += 256) {
            int r = i >> 5, kk = i & 31;
            int row = row0 + r;
            float v = (row < n) ? x[(size_t)row * 128 + k0 + kk] : 0.0f;
            if (relu_in) v = fmaxf(v, 0.0f);
            xs[r][kk] = v;
        }
        for (int i = tid; i < BK * BN; i += 256) {
            int kk = i >> 7, c = i & 127;
            ws[kk][c] = W[(size_t)(k0 + kk) * KOUT + col0 + c];
        }
        __syncthreads();
#pragma unroll 4
        for (int kk = 0; kk < BK; ++kk) {
            float4 w0 = *reinterpret_cast<const float4*>(&ws[kk][tcol * 4]);
            float4 w1 = *reinterpret_cast<const float4*>(&ws[kk][tcol * 4 + 64]);
            float xr[4];
#pragma unroll
            for (int r = 0; r < 4; ++r) xr[r] = xs[trow * 4 + r][kk];
#pragma unroll
            for (int r = 0; r < 4; ++r) {
                acc[r][0] = fmaf(xr[r], w0.x, acc[r][0]);
                acc[r][1] = fmaf(xr[r], w0.y, acc[r][1]);
                acc[r][2] = fmaf(xr[r], w0.z, acc[r][2]);
                acc[r][3] = fmaf(xr[r], w0.w, acc[r][3]);
                acc[r][4] = fmaf(xr[r], w1.x, acc[r][4]);
                acc[r][5] = fmaf(xr[r], w1.y, acc[r][5]);
                acc[r][6] = fmaf(xr[r], w1.z, acc[r][6]);
                acc[r][7] = fmaf(xr[r], w1.w, acc[r][7]);
            }
        }
        __syncthreads();
    }
#pragma unroll
    for (int r = 0; r < 4; ++r) {
        int row = row0 + trow * 4 + r;
        if (row < n) {
            float4 o0 = {acc[r][0], acc[r][1], acc[r][2], acc[r][3]};
            float4 o1 = {acc[r][4], acc[r][5], acc[r][6], acc[r][7]};
            *reinterpret_cast<float4*>(&f[(size_t)row * KOUT + col0 + tcol * 4]) = o0;
            *reinterpret_cast<float4*>(&f[(size_t)row * KOUT + col0 + tcol * 4 + 64]) = o1;
        }
    }
}

// ============================ el/er for layers 0/1 (f is N x 128, C=32 per head) ============================
__global__ void elr_kernel(const float* __restrict__ f, const float* __restrict__ al,
                           const float* __restrict__ ar, float* __restrict__ el,
                           float* __restrict__ er, int nh) {
    int idx = blockIdx.x * blockDim.x + threadIdx.x;
    if (idx >= nh) return;
    int node = idx >> 2, h = idx & 3;
    const float* fp = f + (size_t)node * 128 + h * 32;
    float sl = 0.0f, sr = 0.0f;
#pragma unroll
    for (int c = 0; c < 32; ++c) {
        float v = fp[c];
        sl = fmaf(v, al[h * 32 + c], sl);
        sr = fmaf(v, ar[h * 32 + c], sr);
    }
    el[idx] = sl;
    er[idx] = sr;
}

// ============================ wave-per-node fused softmax + gather (K=128) ============================
__global__ __launch_bounds__(256) void aggr_wave128(const int* __restrict__ rs,
                                                    const int* __restrict__ csrc,
                                                    const float* __restrict__ el,
                                                    const float* __restrict__ er,
                                                    const float* __restrict__ f,
                                                    float* __restrict__ out, int n) {
    const int d = blockIdx.x * 4 + (threadIdx.x >> 6);
    if (d >= n) return;
    const int lane = threadIdx.x & 63;
    const int h = lane >> 4;  // cols lane*2,lane*2+1 are in head lane>>4
    const int e0 = rs[d], e1 = rs[d + 1];
    const float erd = er[d * HH + h];

    float m = -1e30f;
    for (int e = e0 + (lane & 15); e < e1; e += 16) {
        float v = el[csrc[e] * HH + h] + erd;
        v = (v >= 0.0f) ? v : 0.2f * v;
        m = fmaxf(m, v);
    }
#pragma unroll
    for (int off = 1; off < 16; off <<= 1) m = fmaxf(m, __shfl_xor(m, off));

    float z = 0.0f;
    for (int e = e0 + (lane & 15); e < e1; e += 16) {
        float v = el[csrc[e] * HH + h] + erd;
        v = (v >= 0.0f) ? v : 0.2f * v;
        z += __expf(v - m);
    }
#pragma unroll
    for (int off = 1; off < 16; off <<= 1) z += __shfl_xor(z, off);
    const float rz = (z > 0.0f) ? 1.0f / z : 0.0f;

    float a0 = 0.0f, a1 = 0.0f;
    const int cb = lane * 2;
    int e = e0;
    for (; e + 1 < e1; e += 2) {
        int s0 = csrc[e], s1 = csrc[e + 1];
        float v0 = el[s0 * HH + h] + erd;
        float v1 = el[s1 * HH + h] + erd;
        float2 x0 = *reinterpret_cast<const float2*>(&f[(size_t)s0 * 128 + cb]);
        float2 x1 = *reinterpret_cast<const float2*>(&f[(size_t)s1 * 128 + cb]);
        v0 = (v0 >= 0.0f) ? v0 : 0.2f * v0;
        v1 = (v1 >= 0.0f) ? v1 : 0.2f * v1;
        float al0_ = __expf(v0 - m) * rz;
        float al1_ = __expf(v1 - m) * rz;
        a0 = fmaf(al0_, x0.x, a0);
        a1 = fmaf(al0_, x0.y, a1);
        a0 = fmaf(al1_, x1.x, a0);
        a1 = fmaf(al1_, x1.y, a1);
    }
    if (e < e1) {
        int s = csrc[e];
        float v = el[s * HH + h] + erd;
        v = (v >= 0.0f) ? v : 0.2f * v;
        float alf = __expf(v - m) * rz;
        float2 xv = *reinterpret_cast<const float2*>(&f[(size_t)s * 128 + cb]);
        a0 = fmaf(alf, xv.x, a0);
        a1 = fmaf(alf, xv.y, a1);
    }
    *reinterpret_cast<float2*>(&out[(size_t)d * 128 + cb]) = make_float2(a0, a1);
}

// ============================ layer 2: wl/wr = W2_h @ al2_h (128 per head) ============================
__global__ void prep_wlr(const float* __restrict__ W2, const float* __restrict__ al2,
                         const float* __restrict__ ar2, float* __restrict__ wl,
                         float* __restrict__ wr) {
    int idx = blockIdx.x * blockDim.x + threadIdx.x;
    if (idx >= 512) return;
    int h = idx >> 7, i = idx & 127;
    float sl = 0.0f, sr = 0.0f;
    for (int c = 0; c < 128; ++c) {
        float w = W2[(size_t)i * 512 + h * 128 + c];
        sl = fmaf(w, al2[h * 128 + c], sl);
        sr = fmaf(w, ar2[h * 128 + c], sr);
    }
    wl[idx] = sl;
    wr[idx] = sr;
}

// ============================ layer 2 scores: el[n,h] = relu(x[n]) . wl[h] ============================
// 32 nodes per block; x rows staged in LDS.
__global__ __launch_bounds__(256) void elr2_kernel(const float* __restrict__ x,
                                                   const float* __restrict__ wl,
                                                   const float* __restrict__ wr,
                                                   float* __restrict__ el,
                                                   float* __restrict__ er, int n) {
    __shared__ float xls[32][129];
    const int node0 = blockIdx.x * 32;
    const int tid = threadIdx.x;
    for (int i = tid; i < 32 * 128; i += 256) {
        int r = i >> 7, c = i & 127;
        int row = node0 + r;
        xls[r][c] = (row < n) ? fmaxf(x[(size_t)row * 128 + c], 0.0f) : 0.0f;
    }
    __syncthreads();
    const int r = tid >> 3;          // node within block
    const int j = tid & 7;           // 0..3 -> el head j, 4..7 -> er head j-4
    const int node = node0 + r;
    if (node >= n) return;
    const float* wp = (j < 4) ? &wl[(j & 3) * 128] : &wr[(j & 3) * 128];
    float s = 0.0f;
    for (int k = 0; k < 128; k += 4) {
        s = fmaf(xls[r][k], wp[k], s);
        s = fmaf(xls[r][k + 1], wp[k + 1], s);
        s = fmaf(xls[r][k + 2], wp[k + 2], s);
        s = fmaf(xls[r][k + 3], wp[k + 3], s);
    }
    if (j < 4) el[node * HH + j] = s;
    else       er[node * HH + (j & 3)] = s;
}

// ============================ layer 2: aggregate relu(x[src]) with 4 per-head alphas ============================
// agg[d, h*128 + c] = sum_e alpha[e,h] * relu(x[src_e, c])
__global__ __launch_bounds__(256) void aggr_x(const int* __restrict__ rs,
                                              const int* __restrict__ csrc,
                                              const float* __restrict__ el,
                                              const float* __restrict__ er,
                                              const float* __restrict__ x,
                                              float* __restrict__ agg, int n) {
    const int d = blockIdx.x * 4 + (threadIdx.x >> 6);
    if (d >= n) return;
    const int lane = threadIdx.x & 63;
    const int hg = lane >> 4;  // stats head for this lane group
    const int e0 = rs[d], e1 = rs[d + 1];
    float4 er4v = *reinterpret_cast<const float4*>(&er[d * HH]);
    float era[4] = {er4v.x, er4v.y, er4v.z, er4v.w};
    const float erd = era[hg];

    float m = -1e30f;
    for (int e = e0 + (lane & 15); e < e1; e += 16) {
        float v = el[csrc[e] * HH + hg] + erd;
        v = (v >= 0.0f) ? v : 0.2f * v;
        m = fmaxf(m, v);
    }
#pragma unroll
    for (int off = 1; off < 16; off <<= 1) m = fmaxf(m, __shfl_xor(m, off));

    float z = 0.0f;
    for (int e = e0 + (lane & 15); e < e1; e += 16) {
        float v = el[csrc[e] * HH + hg] + erd;
        v = (v >= 0.0f) ? v : 0.2f * v;
        z += __expf(v - m);
    }
#pragma unroll
    for (int off = 1; off < 16; off <<= 1) z += __shfl_xor(z, off);

    float mh[4], rzh[4];
#pragma unroll
    for (int hh = 0; hh < 4; ++hh) {
        mh[hh] = __shfl(m, hh * 16);
        float zz = __shfl(z, hh * 16);
        rzh[hh] = (zz > 0.0f) ? 1.0f / zz : 0.0f;
    }

    float acc[4][2];
#pragma unroll
    for (int hh = 0; hh < 4; ++hh) acc[hh][0] = acc[hh][1] = 0.0f;
    const int cb = lane * 2;
    for (int e = e0; e < e1; ++e) {
        int s = csrc[e];
        float4 el4v = *reinterpret_cast<const float4*>(&el[s * HH]);
        float ela[4] = {el4v.x, el4v.y, el4v.z, el4v.w};
        float2 xv = *reinterpret_cast<const float2*>(&x[(size_t)s * 128 + cb]);
        xv.x = fmaxf(xv.x, 0.0f);
        xv.y = fmaxf(xv.y, 0.0f);
#pragma unroll
        for (int hh = 0; hh < 4; ++hh) {
            float v = ela[hh] + era[hh];
            v = (v >= 0.0f) ? v : 0.2f * v;
            float alf = __expf(v - mh[hh]) * rzh[hh];
            acc[hh][0] = fmaf(alf, xv.x, acc[hh][0]);
            acc[hh][1] = fmaf(alf, xv.y, acc[hh][1]);
        }
    }
#pragma unroll
    for (int hh = 0; hh < 4; ++hh)
        *reinterpret_cast<float2*>(&agg[(size_t)d * 512 + hh * 128 + cb]) =
            make_float2(acc[hh][0], acc[hh][1]);
}

// ============================ layer 2: block-diag GEMM + relu + global max pool ============================
// out block h: agg[:, h*128 + k] @ W2[k, h*128 + c]; epilogue: relu + column max + atomicMax.
__global__ __launch_bounds__(256) void gemm_bd_pool(const float* __restrict__ agg,
                                                    const float* __restrict__ W2,
                                                    unsigned* __restrict__ pooled, int n) {
    constexpr int BM = 64, BK = 32, BN = 128;
    __shared__ float xs[BM][BK + 1];
    __shared__ float ws[BK][BN];
    __shared__ float smax[16][BN];
    const int row0 = blockIdx.x * BM;
    const int col0 = blockIdx.y * BN;  // == head block offset
    const int tid = threadIdx.x;
    const int trow = tid >> 4;
    const int tcol = tid & 15;

    float acc[4][8];
#pragma unroll
    for (int r = 0; r < 4; ++r)
#pragma unroll
        for (int j = 0; j < 8; ++j) acc[r][j] = 0.0f;

    for (int k0 = 0; k0 < 128; k0 += BK) {
        for (int i = tid; i < BM * BK; i += 256) {
            int r = i >> 5, kk = i & 31;
            int row = row0 + r;
            xs[r][kk] = (row < n) ? agg[(size_t)row * 512 + col0 + k0 + kk] : 0.0f;
        }
        for (int i = tid; i < BK * BN; i += 256) {
            int kk = i >> 7, c = i & 127;
            ws[kk][c] = W2[(size_t)(k0 + kk) * 512 + col0 + c];
        }
        __syncthreads();
#pragma unroll 4
        for (int kk = 0; kk < BK; ++kk) {
            float4 w0 = *reinterpret_cast<const float4*>(&ws[kk][tcol * 4]);
            float4 w1 = *reinterpret_cast<const float4*>(&ws[kk][tcol * 4 + 64]);
            float xr[4];
#pragma unroll
            for (int r = 0; r < 4; ++r) xr[r] = xs[trow * 4 + r][kk];
#pragma unroll
            for (int r = 0; r < 4; ++r) {
                acc[r][0] = fmaf(xr[r], w0.x, acc[r][0]);
                acc[r][1] = fmaf(xr[r], w0.y, acc[r][1]);
                acc[r][2] = fmaf(xr[r], w0.z, acc[r][2]);
                acc[r][3] = fmaf(xr[r], w0.w, acc[r][3]);
                acc[r][4] = fmaf(xr[r], w1.x, acc[r][4]);
                acc[r][5] = fmaf(xr[r], w1.y, acc[r][5]);
                acc[r][6] = fmaf(xr[r], w1.z, acc[r][6]);
                acc[r][7] = fmaf(xr[r], w1.w, acc[r][7]);
            }
        }
        __syncthreads();
    }
    // epilogue: relu + per-block column max
    float cm[8];
#pragma unroll
    for (int j = 0; j < 8; ++j) {
        float v = fmaxf(fmaxf(acc[0][j], acc[1][j]), fmaxf(acc[2][j], acc[3][j]));
        cm[j] = fmaxf(v, 0.0f);
    }
#pragma unroll
    for (int j = 0; j < 4; ++j) {
        smax[trow][tcol * 4 + j] = cm[j];
        smax[trow][tcol * 4 + 64 + j] = cm[4 + j];
    }
    __syncthreads();
    if (tid < BN) {
        float mx = 0.0f;
#pragma unroll
        for (int t = 0; t < 16; ++t) mx = fmaxf(mx, smax[t][tid]);
        atomicMax(&pooled[col0 + tid], __float_as_uint(mx));  // nonneg: uint order == float order
    }
}

// ============================ FC head + softmax ============================
__global__ void head_kernel(const float* __restrict__ pooled, const float* __restrict__ fcw,
                            const float* __restrict__ fcb, float* __restrict__ out) {
    __shared__ float logits[8];
    int t = threadIdx.x;
    if (t < 8) {
        float acc = fcb[t];
        for (int i = 0; i < 512; ++i) acc = fmaf(pooled[i], fcw[i * 8 + t], acc);
        logits[t] = acc;
    }
    __syncthreads();
    if (t == 0) {
        float mx = -1e30f;
        for (int j = 0; j < 8; ++j) mx = fmaxf(mx, logits[j]);
        float ex[8], s = 0.0f;
        for (int j = 0; j < 8; ++j) { ex[j] = expf(logits[j] - mx); s += ex[j]; }
        for (int j = 0; j < 8; ++j) out[j] = ex[j] / s;
    }
}

extern "C" void kernel_launch(void* const* d_in, const int* in_sizes, int n_in,
                              void* d_out, int out_size, void* d_ws, size_t ws_size,
                              hipStream_t stream) {
    const float* x0  = (const float*)d_in[0];
    const int*   src = (const int*)d_in[1];
    const int*   dst = (const int*)d_in[2];
    const float* W0  = (const float*)d_in[3];
    const float* al0 = (const float*)d_in[4];
    const float* ar0 = (const float*)d_in[5];
    const float* W1  = (const float*)d_in[6];
    const float* al1 = (const float*)d_in[7];
    const float* ar1 = (const float*)d_in[8];
    const float* W2  = (const float*)d_in[9];
    const float* al2 = (const float*)d_in[10];
    const float* ar2 = (const float*)d_in[11];
    const float* fcw = (const float*)d_in[12];
    const float* fcb = (const float*)d_in[13];
    float* outp = (float*)d_out;

    const int N = in_sizes[0] / 128;
    const int E = in_sizes[1];

    // -------- workspace layout (floats) --------
    float* F    = (float*)d_ws;                  // N*128 projected features (layers 0/1)
    float* B0   = F + (size_t)N * 128;           // N*128 layer-0 out
    float* B1   = B0 + (size_t)N * 128;          // N*128 layer-1 out
    float* AGG  = B1 + (size_t)N * 128;          // N*512 layer-2 aggregated x
    float* el   = AGG + (size_t)N * 512;         // N*4
    float* er   = el + (size_t)N * HH;           // N*4
    float* wl   = er + (size_t)N * HH;           // 512
    float* wr   = wl + 512;                      // 512
    float* pooled = wr + 512;                    // 512
    int* rs   = (int*)(pooled + 512);            // N+1
    int* deg  = rs + (N + 1);                    // N
    int* cur  = deg + N;                         // N
    int* bsum = cur + N;                         // 64
    int* csrc = bsum + 64;                       // E

    // -------- CSR build (once; graph shared by all 3 layers) --------
    hipMemsetAsync(deg, 0, (size_t)2 * N * sizeof(int), stream);  // deg + cur
    hipMemsetAsync(pooled, 0, 512 * sizeof(float), stream);
    hist_kernel<<<(E + 255) / 256, 256, 0, stream>>>(dst, deg, E);
    const int nb = (N + 1023) / 1024;
    scan_block<<<nb, 1024, 0, stream>>>(deg, rs, bsum, N);
    scan_top<<<1, 64, 0, stream>>>(bsum, nb);
    scan_add<<<(N + 255) / 256, 256, 0, stream>>>(rs, bsum, N);
    scatter_kernel<<<(E + 255) / 256, 256, 0, stream>>>(src, dst, rs, cur, csrc, E);

    const int nh = N * HH;
    const int rowTiles = (N + 63) / 64;
    const int nodeBlocks = (N + 3) / 4;

    // -------- layers 0/1 --------
    gemm_tiled<128><<<dim3(rowTiles, 1), 256, 0, stream>>>(x0, W0, F, 0, N);
    elr_kernel<<<(nh + 255) / 256, 256, 0, stream>>>(F, al0, ar0, el, er, nh);
    aggr_wave128<<<nodeBlocks, 256, 0, stream>>>(rs, csrc, el, er, F, B0, N);

    gemm_tiled<128><<<dim3(rowTiles, 1), 256, 0, stream>>>(B0, W1, F, 1, N);
    elr_kernel<<<(nh + 255) / 256, 256, 0, stream>>>(F, al1, ar1, el, er, nh);
    aggr_wave128<<<nodeBlocks, 256, 0, stream>>>(rs, csrc, el, er, F, B1, N);

    // -------- layer 2 (aggregate-then-project) --------
    prep_wlr<<<2, 256, 0, stream>>>(W2, al2, ar2, wl, wr);
    elr2_kernel<<<(N + 31) / 32, 256, 0, stream>>>(B1, wl, wr, el, er, N);
    aggr_x<<<nodeBlocks, 256, 0, stream>>>(rs, csrc, el, er, B1, AGG, N);
    gemm_bd_pool<<<dim3(rowTiles, 4), 256, 0, stream>>>(AGG, W2, (unsigned*)pooled, N);

    head_kernel<<<1, 64, 0, stream>>>(pooled, fcw, fcb, outp);
}

// Round 5
// 414.729 us; speedup vs baseline: 6.8161x; 1.0650x over previous
//
#include <hip/hip_runtime.h>

#define HH 4  // heads

__device__ __forceinline__ float lrelu(float v) { return (v >= 0.0f) ? v : 0.2f * v; }

// ============================ CSR build ============================
__global__ void hist_kernel(const int* __restrict__ dst, int* __restrict__ deg, int E) {
    int i = blockIdx.x * blockDim.x + threadIdx.x;
    if (i < E) atomicAdd(&deg[dst[i]], 1);
}

__global__ void scan_block(const int* __restrict__ deg, int* __restrict__ rs,
                           int* __restrict__ bsum, int n) {
    __shared__ int buf[1024];
    int i = blockIdx.x * 1024 + threadIdx.x;
    int v = (i < n) ? deg[i] : 0;
    buf[threadIdx.x] = v;
    __syncthreads();
    for (int off = 1; off < 1024; off <<= 1) {
        int t = (threadIdx.x >= off) ? buf[threadIdx.x - off] : 0;
        __syncthreads();
        buf[threadIdx.x] += t;
        __syncthreads();
    }
    if (i < n) rs[i + 1] = buf[threadIdx.x];
    if (threadIdx.x == 1023) bsum[blockIdx.x] = buf[1023];
}

__global__ void scan_top(int* bsum, int nb) {
    if (threadIdx.x == 0 && blockIdx.x == 0) {
        int acc = 0;
        for (int b = 0; b < nb; ++b) { int t = bsum[b]; bsum[b] = acc; acc += t; }
    }
}

__global__ void scan_add(int* __restrict__ rs, const int* __restrict__ bsum, int n) {
    int i = blockIdx.x * blockDim.x + threadIdx.x;
    if (i == 0) rs[0] = 0;
    if (i < n) rs[i + 1] += bsum[i >> 10];
}

__global__ void scatter_kernel(const int* __restrict__ src, const int* __restrict__ dst,
                               const int* __restrict__ rs, int* __restrict__ cur,
                               int* __restrict__ csrc, int E) {
    int i = blockIdx.x * blockDim.x + threadIdx.x;
    if (i >= E) return;
    int d = dst[i];
    int p = rs[d] + atomicAdd(&cur[d], 1);
    csrc[p] = src[i];
}

// ============================ tiled GEMM: 64 rows x 128 cols per block ============================
template <int KOUT>
__global__ __launch_bounds__(256) void gemm_tiled(const float* __restrict__ x,
                                                  const float* __restrict__ W,
                                                  float* __restrict__ f, int relu_in, int n) {
    constexpr int BM = 64, BK = 32, BN = 128;
    __shared__ float xs[BM][BK + 1];
    __shared__ float ws[BK][BN];
    const int row0 = blockIdx.x * BM;
    const int col0 = blockIdx.y * BN;
    const int tid = threadIdx.x;
    const int trow = tid >> 4;
    const int tcol = tid & 15;

    float acc[4][8];
#pragma unroll
    for (int r = 0; r < 4; ++r)
#pragma unroll
        for (int j = 0; j < 8; ++j) acc[r][j] = 0.0f;

    for (int k0 = 0; k0 < 128; k0 += BK) {
        for (int i = tid; i < BM * BK; i += 256) {
            int r = i >> 5, kk = i & 31;
            int row = row0 + r;
            float v = (row < n) ? x[(size_t)row * 128 + k0 + kk] : 0.0f;
            if (relu_in) v = fmaxf(v, 0.0f);
            xs[r][kk] = v;
        }
        for (int i = tid; i < BK * BN; i += 256) {
            int kk = i >> 7, c = i & 127;
            ws[kk][c] = W[(size_t)(k0 + kk) * KOUT + col0 + c];
        }
        __syncthreads();
#pragma unroll 4
        for (int kk = 0; kk < BK; ++kk) {
            float4 w0 = *reinterpret_cast<const float4*>(&ws[kk][tcol * 4]);
            float4 w1 = *reinterpret_cast<const float4*>(&ws[kk][tcol * 4 + 64]);
            float xr[4];
#pragma unroll
            for (int r = 0; r < 4; ++r) xr[r] = xs[trow * 4 + r][kk];
#pragma unroll
            for (int r = 0; r < 4; ++r) {
                acc[r][0] = fmaf(xr[r], w0.x, acc[r][0]);
                acc[r][1] = fmaf(xr[r], w0.y, acc[r][1]);
                acc[r][2] = fmaf(xr[r], w0.z, acc[r][2]);
                acc[r][3] = fmaf(xr[r], w0.w, acc[r][3]);
                acc[r][4] = fmaf(xr[r], w1.x, acc[r][4]);
                acc[r][5] = fmaf(xr[r], w1.y, acc[r][5]);
                acc[r][6] = fmaf(xr[r], w1.z, acc[r][6]);
                acc[r][7] = fmaf(xr[r], w1.w, acc[r][7]);
            }
        }
        __syncthreads();
    }
#pragma unroll
    for (int r = 0; r < 4; ++r) {
        int row = row0 + trow * 4 + r;
        if (row < n) {
            float4 o0 = {acc[r][0], acc[r][1], acc[r][2], acc[r][3]};
            float4 o1 = {acc[r][4], acc[r][5], acc[r][6], acc[r][7]};
            *reinterpret_cast<float4*>(&f[(size_t)row * KOUT + col0 + tcol * 4]) = o0;
            *reinterpret_cast<float4*>(&f[(size_t)row * KOUT + col0 + tcol * 4 + 64]) = o1;
        }
    }
}

// ============================ el/er for layers 0/1 ============================
__global__ void elr_kernel(const float* __restrict__ f, const float* __restrict__ al,
                           const float* __restrict__ ar, float* __restrict__ el,
                           float* __restrict__ er, int nh) {
    int idx = blockIdx.x * blockDim.x + threadIdx.x;
    if (idx >= nh) return;
    int node = idx >> 2, h = idx & 3;
    const float* fp = f + (size_t)node * 128 + h * 32;
    float sl = 0.0f, sr = 0.0f;
#pragma unroll
    for (int c = 0; c < 32; ++c) {
        float v = fp[c];
        sl = fmaf(v, al[h * 32 + c], sl);
        sr = fmaf(v, ar[h * 32 + c], sr);
    }
    el[idx] = sl;
    er[idx] = sr;
}

// ============================ wave-per-node softmax + gather (K=128), max-free ============================
// z-pass: lane (h,j) covers edges stride-16 -> 1 exp per edge-head total.
// gather: 16-edge chunks; lane (h,j) computes alpha[c0+j][h] once; shfl-broadcast.
__global__ __launch_bounds__(256) void aggr_wave128(const int* __restrict__ rs,
                                                    const int* __restrict__ csrc,
                                                    const float* __restrict__ el,
                                                    const float* __restrict__ er,
                                                    const float* __restrict__ f,
                                                    float* __restrict__ out, int n) {
    const int d = blockIdx.x * 4 + (threadIdx.x >> 6);
    if (d >= n) return;
    const int lane = threadIdx.x & 63;
    const int hg = lane >> 4;
    const int j16 = lane & 15;
    const int e0 = rs[d], e1 = rs[d + 1];
    const float erd = er[d * HH + hg];

    float z = 0.0f;
    for (int e = e0 + j16; e < e1; e += 16)
        z += __expf(lrelu(el[csrc[e] * HH + hg] + erd));
#pragma unroll
    for (int off = 1; off < 16; off <<= 1) z += __shfl_xor(z, off);
    const float rz = (z > 0.0f) ? 1.0f / z : 0.0f;

    float a0 = 0.0f, a1 = 0.0f;
    const int cb = lane * 2;
    const int hb = lane & 48;  // hg*16
    for (int c0 = e0; c0 < e1; c0 += 16) {
        int e = c0 + j16;
        int s_mine = 0;
        float amine = 0.0f;
        if (e < e1) {
            s_mine = csrc[e];
            amine = __expf(lrelu(el[s_mine * HH + hg] + erd)) * rz;
        }
        const int cnt = min(16, e1 - c0);
#pragma unroll 4
        for (int jj = 0; jj < cnt; ++jj) {
            int s = __shfl(s_mine, jj);
            float alf = __shfl(amine, hb + jj);
            float2 xv = *reinterpret_cast<const float2*>(&f[(size_t)s * 128 + cb]);
            a0 = fmaf(alf, xv.x, a0);
            a1 = fmaf(alf, xv.y, a1);
        }
    }
    *reinterpret_cast<float2*>(&out[(size_t)d * 128 + cb]) = make_float2(a0, a1);
}

// ============================ layer 2: wl/wr = W2_h @ al2_h ============================
__global__ void prep_wlr(const float* __restrict__ W2, const float* __restrict__ al2,
                         const float* __restrict__ ar2, float* __restrict__ wl,
                         float* __restrict__ wr) {
    int idx = blockIdx.x * blockDim.x + threadIdx.x;
    if (idx >= 512) return;
    int h = idx >> 7, i = idx & 127;
    float sl = 0.0f, sr = 0.0f;
    for (int c = 0; c < 128; ++c) {
        float w = W2[(size_t)i * 512 + h * 128 + c];
        sl = fmaf(w, al2[h * 128 + c], sl);
        sr = fmaf(w, ar2[h * 128 + c], sr);
    }
    wl[idx] = sl;
    wr[idx] = sr;
}

// ============================ layer 2 scores ============================
__global__ __launch_bounds__(256) void elr2_kernel(const float* __restrict__ x,
                                                   const float* __restrict__ wl,
                                                   const float* __restrict__ wr,
                                                   float* __restrict__ el,
                                                   float* __restrict__ er, int n) {
    __shared__ float xls[32][129];
    const int node0 = blockIdx.x * 32;
    const int tid = threadIdx.x;
    for (int i = tid; i < 32 * 128; i += 256) {
        int r = i >> 7, c = i & 127;
        int row = node0 + r;
        xls[r][c] = (row < n) ? fmaxf(x[(size_t)row * 128 + c], 0.0f) : 0.0f;
    }
    __syncthreads();
    const int r = tid >> 3;
    const int j = tid & 7;
    const int node = node0 + r;
    if (node >= n) return;
    const float* wp = (j < 4) ? &wl[(j & 3) * 128] : &wr[(j & 3) * 128];
    float s = 0.0f;
    for (int k = 0; k < 128; k += 4) {
        s = fmaf(xls[r][k], wp[k], s);
        s = fmaf(xls[r][k + 1], wp[k + 1], s);
        s = fmaf(xls[r][k + 2], wp[k + 2], s);
        s = fmaf(xls[r][k + 3], wp[k + 3], s);
    }
    if (j < 4) el[node * HH + j] = s;
    else       er[node * HH + (j & 3)] = s;
}

// ============================ layer 2: aggregate relu(x[src]) with 4 per-head alphas ============================
__global__ __launch_bounds__(256) void aggr_x(const int* __restrict__ rs,
                                              const int* __restrict__ csrc,
                                              const float* __restrict__ el,
                                              const float* __restrict__ er,
                                              const float* __restrict__ x,
                                              float* __restrict__ agg, int n) {
    const int d = blockIdx.x * 4 + (threadIdx.x >> 6);
    if (d >= n) return;
    const int lane = threadIdx.x & 63;
    const int hg = lane >> 4;
    const int j16 = lane & 15;
    const int e0 = rs[d], e1 = rs[d + 1];
    const float erd = er[d * HH + hg];

    // z-pass: one exp per edge-head across the wave
    float z = 0.0f;
    for (int e = e0 + j16; e < e1; e += 16)
        z += __expf(lrelu(el[csrc[e] * HH + hg] + erd));
#pragma unroll
    for (int off = 1; off < 16; off <<= 1) z += __shfl_xor(z, off);
    const float rz = (z > 0.0f) ? 1.0f / z : 0.0f;

    float acc[4][2];
#pragma unroll
    for (int hh = 0; hh < 4; ++hh) acc[hh][0] = acc[hh][1] = 0.0f;
    const int cb = lane * 2;
    for (int c0 = e0; c0 < e1; c0 += 16) {
        int e = c0 + j16;
        int s_mine = 0;
        float amine = 0.0f;
        if (e < e1) {
            s_mine = csrc[e];
            amine = __expf(lrelu(el[s_mine * HH + hg] + erd)) * rz;
        }
        const int cnt = min(16, e1 - c0);
#pragma unroll 2
        for (int jj = 0; jj < cnt; ++jj) {
            int s = __shfl(s_mine, jj);
            float af0 = __shfl(amine, jj);
            float af1 = __shfl(amine, 16 + jj);
            float af2 = __shfl(amine, 32 + jj);
            float af3 = __shfl(amine, 48 + jj);
            float2 xv = *reinterpret_cast<const float2*>(&x[(size_t)s * 128 + cb]);
            xv.x = fmaxf(xv.x, 0.0f);
            xv.y = fmaxf(xv.y, 0.0f);
            acc[0][0] = fmaf(af0, xv.x, acc[0][0]);
            acc[0][1] = fmaf(af0, xv.y, acc[0][1]);
            acc[1][0] = fmaf(af1, xv.x, acc[1][0]);
            acc[1][1] = fmaf(af1, xv.y, acc[1][1]);
            acc[2][0] = fmaf(af2, xv.x, acc[2][0]);
            acc[2][1] = fmaf(af2, xv.y, acc[2][1]);
            acc[3][0] = fmaf(af3, xv.x, acc[3][0]);
            acc[3][1] = fmaf(af3, xv.y, acc[3][1]);
        }
    }
#pragma unroll
    for (int hh = 0; hh < 4; ++hh)
        *reinterpret_cast<float2*>(&agg[(size_t)d * 512 + hh * 128 + cb]) =
            make_float2(acc[hh][0], acc[hh][1]);
}

// ============================ layer 2: block-diag GEMM + relu + global max pool ============================
__global__ __launch_bounds__(256) void gemm_bd_pool(const float* __restrict__ agg,
                                                    const float* __restrict__ W2,
                                                    unsigned* __restrict__ pooled, int n) {
    constexpr int BM = 64, BK = 32, BN = 128;
    __shared__ float xs[BM][BK + 1];
    __shared__ float ws[BK][BN];
    __shared__ float smax[16][BN];
    const int row0 = blockIdx.x * BM;
    const int col0 = blockIdx.y * BN;
    const int tid = threadIdx.x;
    const int trow = tid >> 4;
    const int tcol = tid & 15;

    float acc[4][8];
#pragma unroll
    for (int r = 0; r < 4; ++r)
#pragma unroll
        for (int j = 0; j < 8; ++j) acc[r][j] = 0.0f;

    for (int k0 = 0; k0 < 128; k0 += BK) {
        for (int i = tid; i < BM * BK; i += 256) {
            int r = i >> 5, kk = i & 31;
            int row = row0 + r;
            xs[r][kk] = (row < n) ? agg[(size_t)row * 512 + col0 + k0 + kk] : 0.0f;
        }
        for (int i = tid; i < BK * BN; i += 256) {
            int kk = i >> 7, c = i & 127;
            ws[kk][c] = W2[(size_t)(k0 + kk) * 512 + col0 + c];
        }
        __syncthreads();
#pragma unroll 4
        for (int kk = 0; kk < BK; ++kk) {
            float4 w0 = *reinterpret_cast<const float4*>(&ws[kk][tcol * 4]);
            float4 w1 = *reinterpret_cast<const float4*>(&ws[kk][tcol * 4 + 64]);
            float xr[4];
#pragma unroll
            for (int r = 0; r < 4; ++r) xr[r] = xs[trow * 4 + r][kk];
#pragma unroll
            for (int r = 0; r < 4; ++r) {
                acc[r][0] = fmaf(xr[r], w0.x, acc[r][0]);
                acc[r][1] = fmaf(xr[r], w0.y, acc[r][1]);
                acc[r][2] = fmaf(xr[r], w0.z, acc[r][2]);
                acc[r][3] = fmaf(xr[r], w0.w, acc[r][3]);
                acc[r][4] = fmaf(xr[r], w1.x, acc[r][4]);
                acc[r][5] = fmaf(xr[r], w1.y, acc[r][5]);
                acc[r][6] = fmaf(xr[r], w1.z, acc[r][6]);
                acc[r][7] = fmaf(xr[r], w1.w, acc[r][7]);
            }
        }
        __syncthreads();
    }
    float cm[8];
#pragma unroll
    for (int j = 0; j < 8; ++j) {
        float v = fmaxf(fmaxf(acc[0][j], acc[1][j]), fmaxf(acc[2][j], acc[3][j]));
        cm[j] = fmaxf(v, 0.0f);
    }
#pragma unroll
    for (int j = 0; j < 4; ++j) {
        smax[trow][tcol * 4 + j] = cm[j];
        smax[trow][tcol * 4 + 64 + j] = cm[4 + j];
    }
    __syncthreads();
    if (tid < BN) {
        float mx = 0.0f;
#pragma unroll
        for (int t = 0; t < 16; ++t) mx = fmaxf(mx, smax[t][tid]);
        atomicMax(&pooled[col0 + tid], __float_as_uint(mx));
    }
}

// ============================ FC head + softmax ============================
__global__ void head_kernel(const float* __restrict__ pooled, const float* __restrict__ fcw,
                            const float* __restrict__ fcb, float* __restrict__ out) {
    __shared__ float logits[8];
    int t = threadIdx.x;
    if (t < 8) {
        float acc = fcb[t];
        for (int i = 0; i < 512; ++i) acc = fmaf(pooled[i], fcw[i * 8 + t], acc);
        logits[t] = acc;
    }
    __syncthreads();
    if (t == 0) {
        float mx = -1e30f;
        for (int j = 0; j < 8; ++j) mx = fmaxf(mx, logits[j]);
        float ex[8], s = 0.0f;
        for (int j = 0; j < 8; ++j) { ex[j] = expf(logits[j] - mx); s += ex[j]; }
        for (int j = 0; j < 8; ++j) out[j] = ex[j] / s;
    }
}

extern "C" void kernel_launch(void* const* d_in, const int* in_sizes, int n_in,
                              void* d_out, int out_size, void* d_ws, size_t ws_size,
                              hipStream_t stream) {
    const float* x0  = (const float*)d_in[0];
    const int*   src = (const int*)d_in[1];
    const int*   dst = (const int*)d_in[2];
    const float* W0  = (const float*)d_in[3];
    const float* al0 = (const float*)d_in[4];
    const float* ar0 = (const float*)d_in[5];
    const float* W1  = (const float*)d_in[6];
    const float* al1 = (const float*)d_in[7];
    const float* ar1 = (const float*)d_in[8];
    const float* W2  = (const float*)d_in[9];
    const float* al2 = (const float*)d_in[10];
    const float* ar2 = (const float*)d_in[11];
    const float* fcw = (const float*)d_in[12];
    const float* fcb = (const float*)d_in[13];
    float* outp = (float*)d_out;

    const int N = in_sizes[0] / 128;
    const int E = in_sizes[1];

    // -------- workspace layout (floats) --------
    float* F    = (float*)d_ws;                  // N*128
    float* B0   = F + (size_t)N * 128;           // N*128
    float* B1   = B0 + (size_t)N * 128;          // N*128
    float* AGG  = B1 + (size_t)N * 128;          // N*512
    float* el   = AGG + (size_t)N * 512;         // N*4
    float* er   = el + (size_t)N * HH;           // N*4
    float* wl   = er + (size_t)N * HH;           // 512
    float* wr   = wl + 512;                      // 512
    float* pooled = wr + 512;                    // 512
    int* rs   = (int*)(pooled + 512);            // N+1
    int* deg  = rs + (N + 1);                    // N
    int* cur  = deg + N;                         // N
    int* bsum = cur + N;                         // 64
    int* csrc = bsum + 64;                       // E

    // -------- CSR build --------
    hipMemsetAsync(deg, 0, (size_t)2 * N * sizeof(int), stream);
    hipMemsetAsync(pooled, 0, 512 * sizeof(float), stream);
    hist_kernel<<<(E + 255) / 256, 256, 0, stream>>>(dst, deg, E);
    const int nb = (N + 1023) / 1024;
    scan_block<<<nb, 1024, 0, stream>>>(deg, rs, bsum, N);
    scan_top<<<1, 64, 0, stream>>>(bsum, nb);
    scan_add<<<(N + 255) / 256, 256, 0, stream>>>(rs, bsum, N);
    scatter_kernel<<<(E + 255) / 256, 256, 0, stream>>>(src, dst, rs, cur, csrc, E);

    const int nh = N * HH;
    const int rowTiles = (N + 63) / 64;
    const int nodeBlocks = (N + 3) / 4;

    // -------- layers 0/1 --------
    gemm_tiled<128><<<dim3(rowTiles, 1), 256, 0, stream>>>(x0, W0, F, 0, N);
    elr_kernel<<<(nh + 255) / 256, 256, 0, stream>>>(F, al0, ar0, el, er, nh);
    aggr_wave128<<<nodeBlocks, 256, 0, stream>>>(rs, csrc, el, er, F, B0, N);

    gemm_tiled<128><<<dim3(rowTiles, 1), 256, 0, stream>>>(B0, W1, F, 1, N);
    elr_kernel<<<(nh + 255) / 256, 256, 0, stream>>>(F, al1, ar1, el, er, nh);
    aggr_wave128<<<nodeBlocks, 256, 0, stream>>>(rs, csrc, el, er, F, B1, N);

    // -------- layer 2 (aggregate-then-project) --------
    prep_wlr<<<2, 256, 0, stream>>>(W2, al2, ar2, wl, wr);
    elr2_kernel<<<(N + 31) / 32, 256, 0, stream>>>(B1, wl, wr, el, er, N);
    aggr_x<<<nodeBlocks, 256, 0, stream>>>(rs, csrc, el, er, B1, AGG, N);
    gemm_bd_pool<<<dim3(rowTiles, 4), 256, 0, stream>>>(AGG, W2, (unsigned*)pooled, N);

    head_kernel<<<1, 64, 0, stream>>>(pooled, fcw, fcb, outp);
}

// Round 6
// 393.571 us; speedup vs baseline: 7.1825x; 1.0538x over previous
//
#include <hip/hip_runtime.h>

#define HH 4  // heads

__device__ __forceinline__ float lrelu(float v) { return (v >= 0.0f) ? v : 0.2f * v; }

// ============================ CSR build ============================
__global__ void hist_kernel(const int* __restrict__ dst, int* __restrict__ deg, int E) {
    int i = blockIdx.x * blockDim.x + threadIdx.x;
    if (i < E) atomicAdd(&deg[dst[i]], 1);
}

__global__ void scan_block(const int* __restrict__ deg, int* __restrict__ rs,
                           int* __restrict__ bsum, int n) {
    __shared__ int buf[1024];
    int i = blockIdx.x * 1024 + threadIdx.x;
    int v = (i < n) ? deg[i] : 0;
    buf[threadIdx.x] = v;
    __syncthreads();
    for (int off = 1; off < 1024; off <<= 1) {
        int t = (threadIdx.x >= off) ? buf[threadIdx.x - off] : 0;
        __syncthreads();
        buf[threadIdx.x] += t;
        __syncthreads();
    }
    if (i < n) rs[i + 1] = buf[threadIdx.x];
    if (threadIdx.x == 1023) bsum[blockIdx.x] = buf[1023];
}

__global__ void scan_top(int* bsum, int nb) {
    if (threadIdx.x == 0 && blockIdx.x == 0) {
        int acc = 0;
        for (int b = 0; b < nb; ++b) { int t = bsum[b]; bsum[b] = acc; acc += t; }
    }
}

__global__ void scan_add(int* __restrict__ rs, const int* __restrict__ bsum, int n) {
    int i = blockIdx.x * blockDim.x + threadIdx.x;
    if (i == 0) rs[0] = 0;
    if (i < n) rs[i + 1] += bsum[i >> 10];
}

__global__ void scatter_kernel(const int* __restrict__ src, const int* __restrict__ dst,
                               const int* __restrict__ rs, int* __restrict__ cur,
                               int* __restrict__ csrc, int E) {
    int i = blockIdx.x * blockDim.x + threadIdx.x;
    if (i >= E) return;
    int d = dst[i];
    int p = rs[d] + atomicAdd(&cur[d], 1);
    csrc[p] = src[i];
}

// ============================ GEMM 128->128 with fused el/er epilogue ============================
// 64 rows x 128 cols per block; xs transposed ([kk][r], +1 pad) so the k-inner read is one b128.
template <int RELU_IN>
__global__ __launch_bounds__(256) void gemm128(const float* __restrict__ x,
                                               const float* __restrict__ W,
                                               float* __restrict__ f,
                                               const float* __restrict__ al,
                                               const float* __restrict__ ar,
                                               float* __restrict__ el,
                                               float* __restrict__ er, int n) {
    constexpr int BM = 64, BK = 32;
    __shared__ float xs_t[BK][BM + 1];
    __shared__ float ws[BK][128];
    const int row0 = blockIdx.x * BM;
    const int tid = threadIdx.x;
    const int trow = tid >> 4;
    const int tcol = tid & 15;

    float acc[4][8];
#pragma unroll
    for (int r = 0; r < 4; ++r)
#pragma unroll
        for (int j = 0; j < 8; ++j) acc[r][j] = 0.0f;

    for (int k0 = 0; k0 < 128; k0 += BK) {
        for (int i = tid; i < BM * BK; i += 256) {
            int r = i >> 5, kk = i & 31;
            int row = row0 + r;
            float v = (row < n) ? x[(size_t)row * 128 + k0 + kk] : 0.0f;
            if (RELU_IN) v = fmaxf(v, 0.0f);
            xs_t[kk][r] = v;
        }
        for (int i = tid; i < BK * 128; i += 256) {
            int kk = i >> 7, c = i & 127;
            ws[kk][c] = W[(size_t)(k0 + kk) * 128 + c];
        }
        __syncthreads();
#pragma unroll 4
        for (int kk = 0; kk < BK; ++kk) {
            float4 xr = *reinterpret_cast<const float4*>(&xs_t[kk][trow * 4]);
            float4 w0 = *reinterpret_cast<const float4*>(&ws[kk][tcol * 4]);
            float4 w1 = *reinterpret_cast<const float4*>(&ws[kk][tcol * 4 + 64]);
            const float xrr[4] = {xr.x, xr.y, xr.z, xr.w};
#pragma unroll
            for (int r = 0; r < 4; ++r) {
                acc[r][0] = fmaf(xrr[r], w0.x, acc[r][0]);
                acc[r][1] = fmaf(xrr[r], w0.y, acc[r][1]);
                acc[r][2] = fmaf(xrr[r], w0.z, acc[r][2]);
                acc[r][3] = fmaf(xrr[r], w0.w, acc[r][3]);
                acc[r][4] = fmaf(xrr[r], w1.x, acc[r][4]);
                acc[r][5] = fmaf(xrr[r], w1.y, acc[r][5]);
                acc[r][6] = fmaf(xrr[r], w1.z, acc[r][6]);
                acc[r][7] = fmaf(xrr[r], w1.w, acc[r][7]);
            }
        }
        __syncthreads();
    }
    // store f
#pragma unroll
    for (int r = 0; r < 4; ++r) {
        int row = row0 + trow * 4 + r;
        if (row < n) {
            float4 o0 = {acc[r][0], acc[r][1], acc[r][2], acc[r][3]};
            float4 o1 = {acc[r][4], acc[r][5], acc[r][6], acc[r][7]};
            *reinterpret_cast<float4*>(&f[(size_t)row * 128 + tcol * 4]) = o0;
            *reinterpret_cast<float4*>(&f[(size_t)row * 128 + tcol * 4 + 64]) = o1;
        }
    }
    // fused el/er: cols tcol*4..+3 belong to head (tcol>>3), cols 64+tcol*4..+3 to head 2+(tcol>>3)
    const int h_lo = tcol >> 3;
    const int c4 = (tcol & 7) * 4;
    const float* al_lo = &al[h_lo * 32 + c4];
    const float* ar_lo = &ar[h_lo * 32 + c4];
    const float* al_hi = &al[(h_lo + 2) * 32 + c4];
    const float* ar_hi = &ar[(h_lo + 2) * 32 + c4];
    float red[16];
#pragma unroll
    for (int r = 0; r < 4; ++r) {
        float sl = 0.0f, sr = 0.0f, tl = 0.0f, tr = 0.0f;
#pragma unroll
        for (int j = 0; j < 4; ++j) {
            sl = fmaf(acc[r][j], al_lo[j], sl);
            sr = fmaf(acc[r][j], ar_lo[j], sr);
            tl = fmaf(acc[r][4 + j], al_hi[j], tl);
            tr = fmaf(acc[r][4 + j], ar_hi[j], tr);
        }
        red[r] = sl; red[4 + r] = sr; red[8 + r] = tl; red[12 + r] = tr;
    }
#pragma unroll
    for (int off = 1; off < 8; off <<= 1) {
#pragma unroll
        for (int t = 0; t < 16; ++t) red[t] += __shfl_xor(red[t], off);
    }
    if ((tcol & 7) == 0) {
#pragma unroll
        for (int r = 0; r < 4; ++r) {
            int row = row0 + trow * 4 + r;
            if (row < n) {
                el[row * HH + h_lo] = red[r];
                er[row * HH + h_lo] = red[4 + r];
                el[row * HH + h_lo + 2] = red[8 + r];
                er[row * HH + h_lo + 2] = red[12 + r];
            }
        }
    }
}

// ============================ wave-per-node softmax + gather (K=128), max-free ============================
__global__ __launch_bounds__(256) void aggr_wave128(const int* __restrict__ rs,
                                                    const int* __restrict__ csrc,
                                                    const float* __restrict__ el,
                                                    const float* __restrict__ er,
                                                    const float* __restrict__ f,
                                                    float* __restrict__ out, int n) {
    const int d = blockIdx.x * 4 + (threadIdx.x >> 6);
    if (d >= n) return;
    const int lane = threadIdx.x & 63;
    const int hg = lane >> 4;
    const int j16 = lane & 15;
    const int e0 = rs[d], e1 = rs[d + 1];
    const float erd = er[d * HH + hg];

    float z = 0.0f;
    for (int e = e0 + j16; e < e1; e += 16)
        z += __expf(lrelu(el[csrc[e] * HH + hg] + erd));
#pragma unroll
    for (int off = 1; off < 16; off <<= 1) z += __shfl_xor(z, off);
    const float rz = (z > 0.0f) ? 1.0f / z : 0.0f;

    float a0 = 0.0f, a1 = 0.0f;
    const int cb = lane * 2;
    const int hb = lane & 48;
    for (int c0 = e0; c0 < e1; c0 += 16) {
        int e = c0 + j16;
        int s_mine = 0;
        float amine = 0.0f;
        if (e < e1) {
            s_mine = csrc[e];
            amine = __expf(lrelu(el[s_mine * HH + hg] + erd)) * rz;
        }
        const int cnt = min(16, e1 - c0);
#pragma unroll 4
        for (int jj = 0; jj < cnt; ++jj) {
            int s = __shfl(s_mine, jj);
            float alf = __shfl(amine, hb + jj);
            float2 xv = *reinterpret_cast<const float2*>(&f[(size_t)s * 128 + cb]);
            a0 = fmaf(alf, xv.x, a0);
            a1 = fmaf(alf, xv.y, a1);
        }
    }
    *reinterpret_cast<float2*>(&out[(size_t)d * 128 + cb]) = make_float2(a0, a1);
}

// ============================ layer 2: wl/wr = W2_h @ al2_h ============================
__global__ void prep_wlr(const float* __restrict__ W2, const float* __restrict__ al2,
                         const float* __restrict__ ar2, float* __restrict__ wl,
                         float* __restrict__ wr) {
    int idx = blockIdx.x * blockDim.x + threadIdx.x;
    if (idx >= 512) return;
    int h = idx >> 7, i = idx & 127;
    float sl = 0.0f, sr = 0.0f;
    for (int c = 0; c < 128; ++c) {
        float w = W2[(size_t)i * 512 + h * 128 + c];
        sl = fmaf(w, al2[h * 128 + c], sl);
        sr = fmaf(w, ar2[h * 128 + c], sr);
    }
    wl[idx] = sl;
    wr[idx] = sr;
}

// ============================ layer 2 scores ============================
__global__ __launch_bounds__(256) void elr2_kernel(const float* __restrict__ x,
                                                   const float* __restrict__ wl,
                                                   const float* __restrict__ wr,
                                                   float* __restrict__ el,
                                                   float* __restrict__ er, int n) {
    __shared__ float xls[32][129];
    const int node0 = blockIdx.x * 32;
    const int tid = threadIdx.x;
    for (int i = tid; i < 32 * 128; i += 256) {
        int r = i >> 7, c = i & 127;
        int row = node0 + r;
        xls[r][c] = (row < n) ? fmaxf(x[(size_t)row * 128 + c], 0.0f) : 0.0f;
    }
    __syncthreads();
    const int r = tid >> 3;
    const int j = tid & 7;
    const int node = node0 + r;
    if (node >= n) return;
    const float* wp = (j < 4) ? &wl[(j & 3) * 128] : &wr[(j & 3) * 128];
    float s = 0.0f;
    for (int k = 0; k < 128; k += 4) {
        s = fmaf(xls[r][k], wp[k], s);
        s = fmaf(xls[r][k + 1], wp[k + 1], s);
        s = fmaf(xls[r][k + 2], wp[k + 2], s);
        s = fmaf(xls[r][k + 3], wp[k + 3], s);
    }
    if (j < 4) el[node * HH + j] = s;
    else       er[node * HH + (j & 3)] = s;
}

// ============================ layer 2: aggregate relu(x[src]) with 4 per-head alphas ============================
__global__ __launch_bounds__(256) void aggr_x(const int* __restrict__ rs,
                                              const int* __restrict__ csrc,
                                              const float* __restrict__ el,
                                              const float* __restrict__ er,
                                              const float* __restrict__ x,
                                              float* __restrict__ agg, int n) {
    const int d = blockIdx.x * 4 + (threadIdx.x >> 6);
    if (d >= n) return;
    const int lane = threadIdx.x & 63;
    const int hg = lane >> 4;
    const int j16 = lane & 15;
    const int e0 = rs[d], e1 = rs[d + 1];
    const float erd = er[d * HH + hg];

    float z = 0.0f;
    for (int e = e0 + j16; e < e1; e += 16)
        z += __expf(lrelu(el[csrc[e] * HH + hg] + erd));
#pragma unroll
    for (int off = 1; off < 16; off <<= 1) z += __shfl_xor(z, off);
    const float rz = (z > 0.0f) ? 1.0f / z : 0.0f;

    float acc[4][2];
#pragma unroll
    for (int hh = 0; hh < 4; ++hh) acc[hh][0] = acc[hh][1] = 0.0f;
    const int cb = lane * 2;
    for (int c0 = e0; c0 < e1; c0 += 16) {
        int e = c0 + j16;
        int s_mine = 0;
        float amine = 0.0f;
        if (e < e1) {
            s_mine = csrc[e];
            amine = __expf(lrelu(el[s_mine * HH + hg] + erd)) * rz;
        }
        const int cnt = min(16, e1 - c0);
#pragma unroll 2
        for (int jj = 0; jj < cnt; ++jj) {
            int s = __shfl(s_mine, jj);
            float af0 = __shfl(amine, jj);
            float af1 = __shfl(amine, 16 + jj);
            float af2 = __shfl(amine, 32 + jj);
            float af3 = __shfl(amine, 48 + jj);
            float2 xv = *reinterpret_cast<const float2*>(&x[(size_t)s * 128 + cb]);
            xv.x = fmaxf(xv.x, 0.0f);
            xv.y = fmaxf(xv.y, 0.0f);
            acc[0][0] = fmaf(af0, xv.x, acc[0][0]);
            acc[0][1] = fmaf(af0, xv.y, acc[0][1]);
            acc[1][0] = fmaf(af1, xv.x, acc[1][0]);
            acc[1][1] = fmaf(af1, xv.y, acc[1][1]);
            acc[2][0] = fmaf(af2, xv.x, acc[2][0]);
            acc[2][1] = fmaf(af2, xv.y, acc[2][1]);
            acc[3][0] = fmaf(af3, xv.x, acc[3][0]);
            acc[3][1] = fmaf(af3, xv.y, acc[3][1]);
        }
    }
#pragma unroll
    for (int hh = 0; hh < 4; ++hh)
        *reinterpret_cast<float2*>(&agg[(size_t)d * 512 + hh * 128 + cb]) =
            make_float2(acc[hh][0], acc[hh][1]);
}

// ============================ layer 2: block-diag GEMM + relu + global max pool ============================
// xs transposed for b128 reads; pool reduced in-wave (shfl) then via tiny LDS.
__global__ __launch_bounds__(256) void gemm_bd_pool(const float* __restrict__ agg,
                                                    const float* __restrict__ W2,
                                                    unsigned* __restrict__ pooled, int n) {
    constexpr int BM = 64, BK = 32, BN = 128;
    __shared__ float xs_t[BK][BM + 1];
    __shared__ float ws[BK][BN];
    __shared__ float smax[4][BN];
    const int row0 = blockIdx.x * BM;
    const int col0 = blockIdx.y * BN;
    const int tid = threadIdx.x;
    const int trow = tid >> 4;
    const int tcol = tid & 15;
    const int wave = tid >> 6;
    const int lane = tid & 63;

    float acc[4][8];
#pragma unroll
    for (int r = 0; r < 4; ++r)
#pragma unroll
        for (int j = 0; j < 8; ++j) acc[r][j] = 0.0f;

    for (int k0 = 0; k0 < 128; k0 += BK) {
        for (int i = tid; i < BM * BK; i += 256) {
            int r = i >> 5, kk = i & 31;
            int row = row0 + r;
            xs_t[kk][r] = (row < n) ? agg[(size_t)row * 512 + col0 + k0 + kk] : 0.0f;
        }
        for (int i = tid; i < BK * BN; i += 256) {
            int kk = i >> 7, c = i & 127;
            ws[kk][c] = W2[(size_t)(k0 + kk) * 512 + col0 + c];
        }
        __syncthreads();
#pragma unroll 4
        for (int kk = 0; kk < BK; ++kk) {
            float4 xr = *reinterpret_cast<const float4*>(&xs_t[kk][trow * 4]);
            float4 w0 = *reinterpret_cast<const float4*>(&ws[kk][tcol * 4]);
            float4 w1 = *reinterpret_cast<const float4*>(&ws[kk][tcol * 4 + 64]);
            const float xrr[4] = {xr.x, xr.y, xr.z, xr.w};
#pragma unroll
            for (int r = 0; r < 4; ++r) {
                acc[r][0] = fmaf(xrr[r], w0.x, acc[r][0]);
                acc[r][1] = fmaf(xrr[r], w0.y, acc[r][1]);
                acc[r][2] = fmaf(xrr[r], w0.z, acc[r][2]);
                acc[r][3] = fmaf(xrr[r], w0.w, acc[r][3]);
                acc[r][4] = fmaf(xrr[r], w1.x, acc[r][4]);
                acc[r][5] = fmaf(xrr[r], w1.y, acc[r][5]);
                acc[r][6] = fmaf(xrr[r], w1.z, acc[r][6]);
                acc[r][7] = fmaf(xrr[r], w1.w, acc[r][7]);
            }
        }
        __syncthreads();
    }
    // relu + row-max within thread, then trow-reduce within wave via shfl
    float cm[8];
#pragma unroll
    for (int j = 0; j < 8; ++j) {
        float v = fmaxf(fmaxf(acc[0][j], acc[1][j]), fmaxf(acc[2][j], acc[3][j]));
        cm[j] = fmaxf(v, 0.0f);
    }
#pragma unroll
    for (int j = 0; j < 8; ++j) {
        cm[j] = fmaxf(cm[j], __shfl_xor(cm[j], 16));
        cm[j] = fmaxf(cm[j], __shfl_xor(cm[j], 32));
    }
    if (lane < 16) {
#pragma unroll
        for (int j = 0; j < 4; ++j) {
            smax[wave][lane * 4 + j] = cm[j];
            smax[wave][lane * 4 + 64 + j] = cm[4 + j];
        }
    }
    __syncthreads();
    if (tid < BN) {
        float mx = fmaxf(fmaxf(smax[0][tid], smax[1][tid]), fmaxf(smax[2][tid], smax[3][tid]));
        atomicMax(&pooled[col0 + tid], __float_as_uint(mx));  // nonneg: uint order == float order
    }
}

// ============================ FC head + softmax ============================
__global__ void head_kernel(const float* __restrict__ pooled, const float* __restrict__ fcw,
                            const float* __restrict__ fcb, float* __restrict__ out) {
    __shared__ float logits[8];
    int t = threadIdx.x;
    if (t < 8) {
        float acc = fcb[t];
        for (int i = 0; i < 512; ++i) acc = fmaf(pooled[i], fcw[i * 8 + t], acc);
        logits[t] = acc;
    }
    __syncthreads();
    if (t == 0) {
        float mx = -1e30f;
        for (int j = 0; j < 8; ++j) mx = fmaxf(mx, logits[j]);
        float ex[8], s = 0.0f;
        for (int j = 0; j < 8; ++j) { ex[j] = expf(logits[j] - mx); s += ex[j]; }
        for (int j = 0; j < 8; ++j) out[j] = ex[j] / s;
    }
}

extern "C" void kernel_launch(void* const* d_in, const int* in_sizes, int n_in,
                              void* d_out, int out_size, void* d_ws, size_t ws_size,
                              hipStream_t stream) {
    const float* x0  = (const float*)d_in[0];
    const int*   src = (const int*)d_in[1];
    const int*   dst = (const int*)d_in[2];
    const float* W0  = (const float*)d_in[3];
    const float* al0 = (const float*)d_in[4];
    const float* ar0 = (const float*)d_in[5];
    const float* W1  = (const float*)d_in[6];
    const float* al1 = (const float*)d_in[7];
    const float* ar1 = (const float*)d_in[8];
    const float* W2  = (const float*)d_in[9];
    const float* al2 = (const float*)d_in[10];
    const float* ar2 = (const float*)d_in[11];
    const float* fcw = (const float*)d_in[12];
    const float* fcb = (const float*)d_in[13];
    float* outp = (float*)d_out;

    const int N = in_sizes[0] / 128;
    const int E = in_sizes[1];

    // -------- workspace layout (floats) --------
    float* F    = (float*)d_ws;                  // N*128
    float* B0   = F + (size_t)N * 128;           // N*128
    float* B1   = B0 + (size_t)N * 128;          // N*128
    float* AGG  = B1 + (size_t)N * 128;          // N*512
    float* el   = AGG + (size_t)N * 512;         // N*4
    float* er   = el + (size_t)N * HH;           // N*4
    float* wl   = er + (size_t)N * HH;           // 512
    float* wr   = wl + 512;                      // 512
    float* pooled = wr + 512;                    // 512
    int* rs   = (int*)(pooled + 512);            // N+1
    int* deg  = rs + (N + 1);                    // N
    int* cur  = deg + N;                         // N
    int* bsum = cur + N;                         // 64
    int* csrc = bsum + 64;                       // E

    // -------- CSR build --------
    hipMemsetAsync(deg, 0, (size_t)2 * N * sizeof(int), stream);
    hipMemsetAsync(pooled, 0, 512 * sizeof(float), stream);
    hist_kernel<<<(E + 255) / 256, 256, 0, stream>>>(dst, deg, E);
    const int nb = (N + 1023) / 1024;
    scan_block<<<nb, 1024, 0, stream>>>(deg, rs, bsum, N);
    scan_top<<<1, 64, 0, stream>>>(bsum, nb);
    scan_add<<<(N + 255) / 256, 256, 0, stream>>>(rs, bsum, N);
    scatter_kernel<<<(E + 255) / 256, 256, 0, stream>>>(src, dst, rs, cur, csrc, E);

    const int rowTiles = (N + 63) / 64;
    const int nodeBlocks = (N + 3) / 4;

    // -------- layers 0/1 (GEMM with fused el/er) --------
    gemm128<0><<<rowTiles, 256, 0, stream>>>(x0, W0, F, al0, ar0, el, er, N);
    aggr_wave128<<<nodeBlocks, 256, 0, stream>>>(rs, csrc, el, er, F, B0, N);

    gemm128<1><<<rowTiles, 256, 0, stream>>>(B0, W1, F, al1, ar1, el, er, N);
    aggr_wave128<<<nodeBlocks, 256, 0, stream>>>(rs, csrc, el, er, F, B1, N);

    // -------- layer 2 (aggregate-then-project) --------
    prep_wlr<<<2, 256, 0, stream>>>(W2, al2, ar2, wl, wr);
    elr2_kernel<<<(N + 31) / 32, 256, 0, stream>>>(B1, wl, wr, el, er, N);
    aggr_x<<<nodeBlocks, 256, 0, stream>>>(rs, csrc, el, er, B1, AGG, N);
    gemm_bd_pool<<<dim3(rowTiles, 4), 256, 0, stream>>>(AGG, W2, (unsigned*)pooled, N);

    head_kernel<<<1, 64, 0, stream>>>(pooled, fcw, fcb, outp);
}

// Round 7
// 332.375 us; speedup vs baseline: 8.5050x; 1.1841x over previous
//
#include <hip/hip_runtime.h>

#define HH 4  // heads

typedef __attribute__((ext_vector_type(8))) short bf16x8;
typedef __attribute__((ext_vector_type(4))) float f32x4;

__device__ __forceinline__ float lrelu(float v) { return (v >= 0.0f) ? v : 0.2f * v; }

__device__ __forceinline__ unsigned short f2bf(float x) {
    union { float f; unsigned u; } v; v.f = x;
    unsigned r = (v.u + 0x7FFFu + ((v.u >> 16) & 1u)) >> 16;
    return (unsigned short)r;
}
__device__ __forceinline__ float bf2f(unsigned short b) {
    union { unsigned u; float f; } v; v.u = ((unsigned)b) << 16;
    return v.f;
}

// ============================ CSR build ============================
__global__ void hist_kernel(const int* __restrict__ dst, int* __restrict__ deg, int E) {
    int i = blockIdx.x * blockDim.x + threadIdx.x;
    if (i < E) atomicAdd(&deg[dst[i]], 1);
}

__global__ void scan_block(const int* __restrict__ deg, int* __restrict__ rs,
                           int* __restrict__ bsum, int n) {
    __shared__ int buf[1024];
    int i = blockIdx.x * 1024 + threadIdx.x;
    int v = (i < n) ? deg[i] : 0;
    buf[threadIdx.x] = v;
    __syncthreads();
    for (int off = 1; off < 1024; off <<= 1) {
        int t = (threadIdx.x >= off) ? buf[threadIdx.x - off] : 0;
        __syncthreads();
        buf[threadIdx.x] += t;
        __syncthreads();
    }
    if (i < n) rs[i + 1] = buf[threadIdx.x];
    if (threadIdx.x == 1023) bsum[blockIdx.x] = buf[1023];
}

__global__ void scan_top(int* bsum, int nb) {
    if (threadIdx.x == 0 && blockIdx.x == 0) {
        int acc = 0;
        for (int b = 0; b < nb; ++b) { int t = bsum[b]; bsum[b] = acc; acc += t; }
    }
}

__global__ void scan_add(int* __restrict__ rs, const int* __restrict__ bsum, int n) {
    int i = blockIdx.x * blockDim.x + threadIdx.x;
    if (i == 0) rs[0] = 0;
    if (i < n) rs[i + 1] += bsum[i >> 10];
}

__global__ void scatter_kernel(const int* __restrict__ src, const int* __restrict__ dst,
                               const int* __restrict__ rs, int* __restrict__ cur,
                               int* __restrict__ csrc, int E) {
    int i = blockIdx.x * blockDim.x + threadIdx.x;
    if (i >= E) return;
    int d = dst[i];
    int p = rs[d] + atomicAdd(&cur[d], 1);
    csrc[p] = src[i];
}

// ============================ W fragment prepack (bf16 hi/lo, MFMA B-layout) ============================
// tiles 0..31: W0; 32..63: W1; 64..191: W2 y-slices (y = (t-64)>>5).
// B-frag for tile (kt,ct): lane l holds B[kt*32 + (l>>4)*8 + j][ct*16 + (l&15)], j=0..7.
__global__ void prep_wfrag(const float* __restrict__ W0, const float* __restrict__ W1,
                           const float* __restrict__ W2, bf16x8* __restrict__ WFH,
                           bf16x8* __restrict__ WFL) {
    const int wid = blockIdx.x * 4 + (threadIdx.x >> 6);  // 0..191
    if (wid >= 192) return;
    const int l = threadIdx.x & 63;
    const int lr = l & 15, lg = l >> 4;
    int t = wid;
    const float* srcp;
    int stride, coff;
    if (t < 32) { srcp = W0; stride = 128; coff = 0; }
    else if (t < 64) { srcp = W1; stride = 128; coff = 0; t -= 32; }
    else { t -= 64; srcp = W2; stride = 512; coff = (t >> 5) * 128; t &= 31; }
    const int kt = t >> 3, ct = t & 7;
    bf16x8 h8, l8;
#pragma unroll
    for (int j = 0; j < 8; ++j) {
        float w = srcp[(size_t)(kt * 32 + lg * 8 + j) * stride + coff + ct * 16 + lr];
        unsigned short hb = f2bf(w);
        h8[j] = (short)hb;
        l8[j] = (short)f2bf(w - bf2f(hb));
    }
    WFH[(size_t)wid * 64 + l] = h8;
    WFL[(size_t)wid * 64 + l] = l8;
}

// ============================ MFMA GEMM 128->128 (split bf16), fused el/er ============================
// block: 256 threads = 4 waves; wave w: rows blockIdx.x*64 + w*16 .. +15, all 128 cols.
template <int RELU_IN>
__global__ __launch_bounds__(256) void mfma_gemm128(const float* __restrict__ x,
                                                    const bf16x8* __restrict__ BH,
                                                    const bf16x8* __restrict__ BL,
                                                    float* __restrict__ f,
                                                    const float* __restrict__ al,
                                                    const float* __restrict__ ar,
                                                    float* __restrict__ el,
                                                    float* __restrict__ er, int n) {
    const int tid = threadIdx.x;
    const int w = tid >> 6, l = tid & 63;
    const int lr = l & 15, lg = l >> 4;
    const int rowbase = blockIdx.x * 64 + w * 16;
    const int arow = rowbase + lr;

    f32x4 acc[8];
#pragma unroll
    for (int ct = 0; ct < 8; ++ct) acc[ct] = (f32x4){0.f, 0.f, 0.f, 0.f};

    for (int kt = 0; kt < 4; ++kt) {
        float a[8];
        if (arow < n) {
            float4 p0 = *reinterpret_cast<const float4*>(&x[(size_t)arow * 128 + kt * 32 + lg * 8]);
            float4 p1 = *reinterpret_cast<const float4*>(&x[(size_t)arow * 128 + kt * 32 + lg * 8 + 4]);
            a[0] = p0.x; a[1] = p0.y; a[2] = p0.z; a[3] = p0.w;
            a[4] = p1.x; a[5] = p1.y; a[6] = p1.z; a[7] = p1.w;
        } else {
#pragma unroll
            for (int j = 0; j < 8; ++j) a[j] = 0.f;
        }
        bf16x8 ah, alo;
#pragma unroll
        for (int j = 0; j < 8; ++j) {
            float v = RELU_IN ? fmaxf(a[j], 0.f) : a[j];
            unsigned short hb = f2bf(v);
            ah[j] = (short)hb;
            alo[j] = (short)f2bf(v - bf2f(hb));
        }
        const bf16x8* bh = &BH[(size_t)(kt * 8) * 64 + l];
        const bf16x8* bl = &BL[(size_t)(kt * 8) * 64 + l];
#pragma unroll
        for (int ct = 0; ct < 8; ++ct) {
            bf16x8 b1 = bh[ct * 64];
            bf16x8 b2 = bl[ct * 64];
            acc[ct] = __builtin_amdgcn_mfma_f32_16x16x32_bf16(ah, b1, acc[ct], 0, 0, 0);
            acc[ct] = __builtin_amdgcn_mfma_f32_16x16x32_bf16(alo, b1, acc[ct], 0, 0, 0);
            acc[ct] = __builtin_amdgcn_mfma_f32_16x16x32_bf16(ah, b2, acc[ct], 0, 0, 0);
        }
    }
    // store f: D[row = lg*4+reg][col = ct*16+lr]
#pragma unroll
    for (int reg = 0; reg < 4; ++reg) {
        int orow = rowbase + lg * 4 + reg;
        if (orow < n) {
#pragma unroll
            for (int ct = 0; ct < 8; ++ct)
                f[(size_t)orow * 128 + ct * 16 + lr] = acc[ct][reg];
        }
    }
    // fused el/er: head h covers coltiles 2h (in-head col lr) and 2h+1 (in-head col 16+lr)
    float pel[4][4], per_[4][4];
#pragma unroll
    for (int h = 0; h < 4; ++h) {
        float a0 = al[h * 32 + lr], a1 = al[h * 32 + 16 + lr];
        float r0 = ar[h * 32 + lr], r1 = ar[h * 32 + 16 + lr];
#pragma unroll
        for (int reg = 0; reg < 4; ++reg) {
            pel[reg][h] = acc[2 * h][reg] * a0 + acc[2 * h + 1][reg] * a1;
            per_[reg][h] = acc[2 * h][reg] * r0 + acc[2 * h + 1][reg] * r1;
        }
    }
#pragma unroll
    for (int off = 1; off < 16; off <<= 1) {
#pragma unroll
        for (int reg = 0; reg < 4; ++reg)
#pragma unroll
            for (int h = 0; h < 4; ++h) {
                pel[reg][h] += __shfl_xor(pel[reg][h], off);
                per_[reg][h] += __shfl_xor(per_[reg][h], off);
            }
    }
    if (lr == 0) {
#pragma unroll
        for (int reg = 0; reg < 4; ++reg) {
            int orow = rowbase + lg * 4 + reg;
            if (orow < n) {
#pragma unroll
                for (int h = 0; h < 4; ++h) {
                    el[orow * HH + h] = pel[reg][h];
                    er[orow * HH + h] = per_[reg][h];
                }
            }
        }
    }
}

// ============================ MFMA block-diag GEMM + relu + global max pool ============================
__global__ __launch_bounds__(256) void mfma_bd_pool(const float* __restrict__ agg,
                                                    const bf16x8* __restrict__ WFH,
                                                    const bf16x8* __restrict__ WFL,
                                                    unsigned* __restrict__ pooled, int n) {
    __shared__ float smax[4][128];
    const int tid = threadIdx.x;
    const int w = tid >> 6, l = tid & 63;
    const int lr = l & 15, lg = l >> 4;
    const int y = blockIdx.y;
    const int rowbase = blockIdx.x * 64 + w * 16;
    const int arow = rowbase + lr;
    const bf16x8* BH = WFH + (size_t)(64 + y * 32) * 64;
    const bf16x8* BL = WFL + (size_t)(64 + y * 32) * 64;

    f32x4 acc[8];
#pragma unroll
    for (int ct = 0; ct < 8; ++ct) acc[ct] = (f32x4){0.f, 0.f, 0.f, 0.f};

    for (int kt = 0; kt < 4; ++kt) {
        float a[8];
        if (arow < n) {
            float4 p0 = *reinterpret_cast<const float4*>(&agg[(size_t)arow * 512 + y * 128 + kt * 32 + lg * 8]);
            float4 p1 = *reinterpret_cast<const float4*>(&agg[(size_t)arow * 512 + y * 128 + kt * 32 + lg * 8 + 4]);
            a[0] = p0.x; a[1] = p0.y; a[2] = p0.z; a[3] = p0.w;
            a[4] = p1.x; a[5] = p1.y; a[6] = p1.z; a[7] = p1.w;
        } else {
#pragma unroll
            for (int j = 0; j < 8; ++j) a[j] = 0.f;
        }
        bf16x8 ah, alo;
#pragma unroll
        for (int j = 0; j < 8; ++j) {
            unsigned short hb = f2bf(a[j]);
            ah[j] = (short)hb;
            alo[j] = (short)f2bf(a[j] - bf2f(hb));
        }
        const bf16x8* bh = &BH[(size_t)(kt * 8) * 64 + l];
        const bf16x8* bl = &BL[(size_t)(kt * 8) * 64 + l];
#pragma unroll
        for (int ct = 0; ct < 8; ++ct) {
            bf16x8 b1 = bh[ct * 64];
            bf16x8 b2 = bl[ct * 64];
            acc[ct] = __builtin_amdgcn_mfma_f32_16x16x32_bf16(ah, b1, acc[ct], 0, 0, 0);
            acc[ct] = __builtin_amdgcn_mfma_f32_16x16x32_bf16(alo, b1, acc[ct], 0, 0, 0);
            acc[ct] = __builtin_amdgcn_mfma_f32_16x16x32_bf16(ah, b2, acc[ct], 0, 0, 0);
        }
    }
    // relu + column max: reduce over 4 regs, then over the 4 lane-groups (rows), per col ct*16+lr
    float cm[8];
#pragma unroll
    for (int ct = 0; ct < 8; ++ct) {
        float v = fmaxf(fmaxf(acc[ct][0], acc[ct][1]), fmaxf(acc[ct][2], acc[ct][3]));
        cm[ct] = fmaxf(v, 0.f);
    }
#pragma unroll
    for (int ct = 0; ct < 8; ++ct) {
        cm[ct] = fmaxf(cm[ct], __shfl_xor(cm[ct], 16));
        cm[ct] = fmaxf(cm[ct], __shfl_xor(cm[ct], 32));
    }
    if (l < 16) {
#pragma unroll
        for (int ct = 0; ct < 8; ++ct) smax[w][ct * 16 + lr] = cm[ct];
    }
    __syncthreads();
    if (tid < 128) {
        float mx = fmaxf(fmaxf(smax[0][tid], smax[1][tid]), fmaxf(smax[2][tid], smax[3][tid]));
        atomicMax(&pooled[y * 128 + tid], __float_as_uint(mx));  // nonneg: uint order == float order
    }
}

// ============================ wave-per-node softmax + gather (K=128), max-free ============================
__global__ __launch_bounds__(256) void aggr_wave128(const int* __restrict__ rs,
                                                    const int* __restrict__ csrc,
                                                    const float* __restrict__ el,
                                                    const float* __restrict__ er,
                                                    const float* __restrict__ f,
                                                    float* __restrict__ out, int n) {
    const int d = blockIdx.x * 4 + (threadIdx.x >> 6);
    if (d >= n) return;
    const int lane = threadIdx.x & 63;
    const int hg = lane >> 4;
    const int j16 = lane & 15;
    const int e0 = rs[d], e1 = rs[d + 1];
    const float erd = er[d * HH + hg];

    float z = 0.0f;
    for (int e = e0 + j16; e < e1; e += 16)
        z += __expf(lrelu(el[csrc[e] * HH + hg] + erd));
#pragma unroll
    for (int off = 1; off < 16; off <<= 1) z += __shfl_xor(z, off);
    const float rz = (z > 0.0f) ? 1.0f / z : 0.0f;

    float a0 = 0.0f, a1 = 0.0f;
    const int cb = lane * 2;
    const int hb = lane & 48;
    for (int c0 = e0; c0 < e1; c0 += 16) {
        int e = c0 + j16;
        int s_mine = 0;
        float amine = 0.0f;
        if (e < e1) {
            s_mine = csrc[e];
            amine = __expf(lrelu(el[s_mine * HH + hg] + erd)) * rz;
        }
        const int cnt = min(16, e1 - c0);
#pragma unroll 4
        for (int jj = 0; jj < cnt; ++jj) {
            int s = __shfl(s_mine, jj);
            float alf = __shfl(amine, hb + jj);
            float2 xv = *reinterpret_cast<const float2*>(&f[(size_t)s * 128 + cb]);
            a0 = fmaf(alf, xv.x, a0);
            a1 = fmaf(alf, xv.y, a1);
        }
    }
    *reinterpret_cast<float2*>(&out[(size_t)d * 128 + cb]) = make_float2(a0, a1);
}

// ============================ layer 2: wl/wr = W2_h @ al2_h ============================
__global__ void prep_wlr(const float* __restrict__ W2, const float* __restrict__ al2,
                         const float* __restrict__ ar2, float* __restrict__ wl,
                         float* __restrict__ wr) {
    int idx = blockIdx.x * blockDim.x + threadIdx.x;
    if (idx >= 512) return;
    int h = idx >> 7, i = idx & 127;
    float sl = 0.0f, sr = 0.0f;
    for (int c = 0; c < 128; ++c) {
        float w = W2[(size_t)i * 512 + h * 128 + c];
        sl = fmaf(w, al2[h * 128 + c], sl);
        sr = fmaf(w, ar2[h * 128 + c], sr);
    }
    wl[idx] = sl;
    wr[idx] = sr;
}

// ============================ layer 2 scores ============================
__global__ __launch_bounds__(256) void elr2_kernel(const float* __restrict__ x,
                                                   const float* __restrict__ wl,
                                                   const float* __restrict__ wr,
                                                   float* __restrict__ el,
                                                   float* __restrict__ er, int n) {
    __shared__ float xls[32][129];
    const int node0 = blockIdx.x * 32;
    const int tid = threadIdx.x;
    for (int i = tid; i < 32 * 128; i += 256) {
        int r = i >> 7, c = i & 127;
        int row = node0 + r;
        xls[r][c] = (row < n) ? fmaxf(x[(size_t)row * 128 + c], 0.0f) : 0.0f;
    }
    __syncthreads();
    const int r = tid >> 3;
    const int j = tid & 7;
    const int node = node0 + r;
    if (node >= n) return;
    const float* wp = (j < 4) ? &wl[(j & 3) * 128] : &wr[(j & 3) * 128];
    float s = 0.0f;
    for (int k = 0; k < 128; k += 4) {
        s = fmaf(xls[r][k], wp[k], s);
        s = fmaf(xls[r][k + 1], wp[k + 1], s);
        s = fmaf(xls[r][k + 2], wp[k + 2], s);
        s = fmaf(xls[r][k + 3], wp[k + 3], s);
    }
    if (j < 4) el[node * HH + j] = s;
    else       er[node * HH + (j & 3)] = s;
}

// ============================ layer 2: aggregate relu(x[src]) with 4 per-head alphas ============================
__global__ __launch_bounds__(256) void aggr_x(const int* __restrict__ rs,
                                              const int* __restrict__ csrc,
                                              const float* __restrict__ el,
                                              const float* __restrict__ er,
                                              const float* __restrict__ x,
                                              float* __restrict__ agg, int n) {
    const int d = blockIdx.x * 4 + (threadIdx.x >> 6);
    if (d >= n) return;
    const int lane = threadIdx.x & 63;
    const int hg = lane >> 4;
    const int j16 = lane & 15;
    const int e0 = rs[d], e1 = rs[d + 1];
    const float erd = er[d * HH + hg];

    float z = 0.0f;
    for (int e = e0 + j16; e < e1; e += 16)
        z += __expf(lrelu(el[csrc[e] * HH + hg] + erd));
#pragma unroll
    for (int off = 1; off < 16; off <<= 1) z += __shfl_xor(z, off);
    const float rz = (z > 0.0f) ? 1.0f / z : 0.0f;

    float acc[4][2];
#pragma unroll
    for (int hh = 0; hh < 4; ++hh) acc[hh][0] = acc[hh][1] = 0.0f;
    const int cb = lane * 2;
    for (int c0 = e0; c0 < e1; c0 += 16) {
        int e = c0 + j16;
        int s_mine = 0;
        float amine = 0.0f;
        if (e < e1) {
            s_mine = csrc[e];
            amine = __expf(lrelu(el[s_mine * HH + hg] + erd)) * rz;
        }
        const int cnt = min(16, e1 - c0);
#pragma unroll 2
        for (int jj = 0; jj < cnt; ++jj) {
            int s = __shfl(s_mine, jj);
            float af0 = __shfl(amine, jj);
            float af1 = __shfl(amine, 16 + jj);
            float af2 = __shfl(amine, 32 + jj);
            float af3 = __shfl(amine, 48 + jj);
            float2 xv = *reinterpret_cast<const float2*>(&x[(size_t)s * 128 + cb]);
            xv.x = fmaxf(xv.x, 0.0f);
            xv.y = fmaxf(xv.y, 0.0f);
            acc[0][0] = fmaf(af0, xv.x, acc[0][0]);
            acc[0][1] = fmaf(af0, xv.y, acc[0][1]);
            acc[1][0] = fmaf(af1, xv.x, acc[1][0]);
            acc[1][1] = fmaf(af1, xv.y, acc[1][1]);
            acc[2][0] = fmaf(af2, xv.x, acc[2][0]);
            acc[2][1] = fmaf(af2, xv.y, acc[2][1]);
            acc[3][0] = fmaf(af3, xv.x, acc[3][0]);
            acc[3][1] = fmaf(af3, xv.y, acc[3][1]);
        }
    }
#pragma unroll
    for (int hh = 0; hh < 4; ++hh)
        *reinterpret_cast<float2*>(&agg[(size_t)d * 512 + hh * 128 + cb]) =
            make_float2(acc[hh][0], acc[hh][1]);
}

// ============================ FC head + softmax ============================
__global__ void head_kernel(const float* __restrict__ pooled, const float* __restrict__ fcw,
                            const float* __restrict__ fcb, float* __restrict__ out) {
    __shared__ float logits[8];
    int t = threadIdx.x;
    if (t < 8) {
        float acc = fcb[t];
        for (int i = 0; i < 512; ++i) acc = fmaf(pooled[i], fcw[i * 8 + t], acc);
        logits[t] = acc;
    }
    __syncthreads();
    if (t == 0) {
        float mx = -1e30f;
        for (int j = 0; j < 8; ++j) mx = fmaxf(mx, logits[j]);
        float ex[8], s = 0.0f;
        for (int j = 0; j < 8; ++j) { ex[j] = expf(logits[j] - mx); s += ex[j]; }
        for (int j = 0; j < 8; ++j) out[j] = ex[j] / s;
    }
}

extern "C" void kernel_launch(void* const* d_in, const int* in_sizes, int n_in,
                              void* d_out, int out_size, void* d_ws, size_t ws_size,
                              hipStream_t stream) {
    const float* x0  = (const float*)d_in[0];
    const int*   src = (const int*)d_in[1];
    const int*   dst = (const int*)d_in[2];
    const float* W0  = (const float*)d_in[3];
    const float* al0 = (const float*)d_in[4];
    const float* ar0 = (const float*)d_in[5];
    const float* W1  = (const float*)d_in[6];
    const float* al1 = (const float*)d_in[7];
    const float* ar1 = (const float*)d_in[8];
    const float* W2  = (const float*)d_in[9];
    const float* al2 = (const float*)d_in[10];
    const float* ar2 = (const float*)d_in[11];
    const float* fcw = (const float*)d_in[12];
    const float* fcb = (const float*)d_in[13];
    float* outp = (float*)d_out;

    const int N = in_sizes[0] / 128;
    const int E = in_sizes[1];

    // -------- workspace layout (floats; all offsets 16B-aligned) --------
    float* F    = (float*)d_ws;                  // N*128
    float* B0   = F + (size_t)N * 128;           // N*128
    float* B1   = B0 + (size_t)N * 128;          // N*128
    float* AGG  = B1 + (size_t)N * 128;          // N*512
    float* el   = AGG + (size_t)N * 512;         // N*4
    float* er   = el + (size_t)N * HH;           // N*4
    float* wl   = er + (size_t)N * HH;           // 512
    float* wr   = wl + 512;                      // 512
    float* pooled = wr + 512;                    // 512
    int* rs   = (int*)(pooled + 512);            // N+1
    int* deg  = rs + (N + 1);                    // N
    int* cur  = deg + N;                         // N
    int* bsum = cur + N;                         // 64
    int* csrc = bsum + 64;                       // E
    float* wfbase = (float*)(csrc + ((E + 3) & ~3)) + 1;  // bump to next...
    // re-align to 16 B:
    uintptr_t wfaddr = ((uintptr_t)(csrc + E) + 15) & ~(uintptr_t)15;
    bf16x8* WFH = (bf16x8*)wfaddr;               // 192*64 frags * 16 B
    bf16x8* WFL = WFH + (size_t)192 * 64;
    (void)wfbase;

    // -------- CSR build + W prepack --------
    hipMemsetAsync(deg, 0, (size_t)2 * N * sizeof(int), stream);
    hipMemsetAsync(pooled, 0, 512 * sizeof(float), stream);
    prep_wfrag<<<48, 256, 0, stream>>>(W0, W1, W2, WFH, WFL);
    hist_kernel<<<(E + 255) / 256, 256, 0, stream>>>(dst, deg, E);
    const int nb = (N + 1023) / 1024;
    scan_block<<<nb, 1024, 0, stream>>>(deg, rs, bsum, N);
    scan_top<<<1, 64, 0, stream>>>(bsum, nb);
    scan_add<<<(N + 255) / 256, 256, 0, stream>>>(rs, bsum, N);
    scatter_kernel<<<(E + 255) / 256, 256, 0, stream>>>(src, dst, rs, cur, csrc, E);

    const int rowTiles = (N + 63) / 64;
    const int nodeBlocks = (N + 3) / 4;

    // -------- layers 0/1 (MFMA GEMM with fused el/er) --------
    mfma_gemm128<0><<<rowTiles, 256, 0, stream>>>(x0, WFH, WFL, F, al0, ar0, el, er, N);
    aggr_wave128<<<nodeBlocks, 256, 0, stream>>>(rs, csrc, el, er, F, B0, N);

    mfma_gemm128<1><<<rowTiles, 256, 0, stream>>>(B0, WFH + (size_t)32 * 64, WFL + (size_t)32 * 64,
                                                  F, al1, ar1, el, er, N);
    aggr_wave128<<<nodeBlocks, 256, 0, stream>>>(rs, csrc, el, er, F, B1, N);

    // -------- layer 2 (aggregate-then-project) --------
    prep_wlr<<<2, 256, 0, stream>>>(W2, al2, ar2, wl, wr);
    elr2_kernel<<<(N + 31) / 32, 256, 0, stream>>>(B1, wl, wr, el, er, N);
    aggr_x<<<nodeBlocks, 256, 0, stream>>>(rs, csrc, el, er, B1, AGG, N);
    mfma_bd_pool<<<dim3(rowTiles, 4), 256, 0, stream>>>(AGG, WFH, WFL, (unsigned*)pooled, N);

    head_kernel<<<1, 64, 0, stream>>>(pooled, fcw, fcb, outp);
}

// Round 8
// 291.644 us; speedup vs baseline: 9.6928x; 1.1397x over previous
//
#include <hip/hip_runtime.h>

#define HH 4  // heads

typedef __attribute__((ext_vector_type(8))) short bf16x8;
typedef __attribute__((ext_vector_type(4))) float f32x4;

__device__ __forceinline__ float lrelu(float v) { return (v >= 0.0f) ? v : 0.2f * v; }

__device__ __forceinline__ unsigned short f2bf(float x) {
    union { float f; unsigned u; } v; v.f = x;
    unsigned r = (v.u + 0x7FFFu + ((v.u >> 16) & 1u)) >> 16;
    return (unsigned short)r;
}
__device__ __forceinline__ float bf2f(unsigned short b) {
    union { unsigned u; float f; } v; v.u = ((unsigned)b) << 16;
    return v.f;
}

// ============================ CSR build ============================
__global__ void hist_kernel(const int* __restrict__ dst, int* __restrict__ deg, int E) {
    int i = blockIdx.x * blockDim.x + threadIdx.x;
    if (i < E) atomicAdd(&deg[dst[i]], 1);
}

__global__ void scan_block(const int* __restrict__ deg, int* __restrict__ rs,
                           int* __restrict__ bsum, int n) {
    __shared__ int buf[1024];
    int i = blockIdx.x * 1024 + threadIdx.x;
    int v = (i < n) ? deg[i] : 0;
    buf[threadIdx.x] = v;
    __syncthreads();
    for (int off = 1; off < 1024; off <<= 1) {
        int t = (threadIdx.x >= off) ? buf[threadIdx.x - off] : 0;
        __syncthreads();
        buf[threadIdx.x] += t;
        __syncthreads();
    }
    if (i < n) rs[i + 1] = buf[threadIdx.x];
    if (threadIdx.x == 1023) bsum[blockIdx.x] = buf[1023];
}

__global__ void scan_top(int* bsum, int nb) {
    if (threadIdx.x == 0 && blockIdx.x == 0) {
        int acc = 0;
        for (int b = 0; b < nb; ++b) { int t = bsum[b]; bsum[b] = acc; acc += t; }
    }
}

__global__ void scan_add(int* __restrict__ rs, const int* __restrict__ bsum, int n) {
    int i = blockIdx.x * blockDim.x + threadIdx.x;
    if (i == 0) rs[0] = 0;
    if (i < n) rs[i + 1] += bsum[i >> 10];
}

__global__ void scatter_kernel(const int* __restrict__ src, const int* __restrict__ dst,
                               const int* __restrict__ rs, int* __restrict__ cur,
                               int* __restrict__ csrc, int E) {
    int i = blockIdx.x * blockDim.x + threadIdx.x;
    if (i >= E) return;
    int d = dst[i];
    int p = rs[d] + atomicAdd(&cur[d], 1);
    csrc[p] = src[i];
}

// ============================ W fragment prepack (bf16 hi/lo, MFMA B-layout) ============================
__global__ void prep_wfrag(const float* __restrict__ W0, const float* __restrict__ W1,
                           const float* __restrict__ W2, bf16x8* __restrict__ WFH,
                           bf16x8* __restrict__ WFL) {
    const int wid = blockIdx.x * 4 + (threadIdx.x >> 6);  // 0..191
    if (wid >= 192) return;
    const int l = threadIdx.x & 63;
    const int lr = l & 15, lg = l >> 4;
    int t = wid;
    const float* srcp;
    int stride, coff;
    if (t < 32) { srcp = W0; stride = 128; coff = 0; }
    else if (t < 64) { srcp = W1; stride = 128; coff = 0; t -= 32; }
    else { t -= 64; srcp = W2; stride = 512; coff = (t >> 5) * 128; t &= 31; }
    const int kt = t >> 3, ct = t & 7;
    bf16x8 h8, l8;
#pragma unroll
    for (int j = 0; j < 8; ++j) {
        float w = srcp[(size_t)(kt * 32 + lg * 8 + j) * stride + coff + ct * 16 + lr];
        unsigned short hb = f2bf(w);
        h8[j] = (short)hb;
        l8[j] = (short)f2bf(w - bf2f(hb));
    }
    WFH[(size_t)wid * 64 + l] = h8;
    WFL[(size_t)wid * 64 + l] = l8;
}

// ============================ MFMA GEMM 128->128 (split bf16), fused el/er ============================
__global__ __launch_bounds__(256) void mfma_gemm128(const float* __restrict__ x,
                                                    const bf16x8* __restrict__ BH,
                                                    const bf16x8* __restrict__ BL,
                                                    float* __restrict__ f,
                                                    const float* __restrict__ al,
                                                    const float* __restrict__ ar,
                                                    float* __restrict__ el,
                                                    float* __restrict__ er, int n) {
    const int tid = threadIdx.x;
    const int w = tid >> 6, l = tid & 63;
    const int lr = l & 15, lg = l >> 4;
    const int rowbase = blockIdx.x * 64 + w * 16;
    const int arow = rowbase + lr;

    f32x4 acc[8];
#pragma unroll
    for (int ct = 0; ct < 8; ++ct) acc[ct] = (f32x4){0.f, 0.f, 0.f, 0.f};

    for (int kt = 0; kt < 4; ++kt) {
        float a[8];
        if (arow < n) {
            float4 p0 = *reinterpret_cast<const float4*>(&x[(size_t)arow * 128 + kt * 32 + lg * 8]);
            float4 p1 = *reinterpret_cast<const float4*>(&x[(size_t)arow * 128 + kt * 32 + lg * 8 + 4]);
            a[0] = p0.x; a[1] = p0.y; a[2] = p0.z; a[3] = p0.w;
            a[4] = p1.x; a[5] = p1.y; a[6] = p1.z; a[7] = p1.w;
        } else {
#pragma unroll
            for (int j = 0; j < 8; ++j) a[j] = 0.f;
        }
        bf16x8 ah, alo;
#pragma unroll
        for (int j = 0; j < 8; ++j) {
            unsigned short hb = f2bf(a[j]);
            ah[j] = (short)hb;
            alo[j] = (short)f2bf(a[j] - bf2f(hb));
        }
        const bf16x8* bh = &BH[(size_t)(kt * 8) * 64 + l];
        const bf16x8* bl = &BL[(size_t)(kt * 8) * 64 + l];
#pragma unroll
        for (int ct = 0; ct < 8; ++ct) {
            bf16x8 b1 = bh[ct * 64];
            bf16x8 b2 = bl[ct * 64];
            acc[ct] = __builtin_amdgcn_mfma_f32_16x16x32_bf16(ah, b1, acc[ct], 0, 0, 0);
            acc[ct] = __builtin_amdgcn_mfma_f32_16x16x32_bf16(alo, b1, acc[ct], 0, 0, 0);
            acc[ct] = __builtin_amdgcn_mfma_f32_16x16x32_bf16(ah, b2, acc[ct], 0, 0, 0);
        }
    }
    // store f: D[row = lg*4+reg][col = ct*16+lr]
#pragma unroll
    for (int reg = 0; reg < 4; ++reg) {
        int orow = rowbase + lg * 4 + reg;
        if (orow < n) {
#pragma unroll
            for (int ct = 0; ct < 8; ++ct)
                f[(size_t)orow * 128 + ct * 16 + lr] = acc[ct][reg];
        }
    }
    // fused el/er
    float pel[4][4], per_[4][4];
#pragma unroll
    for (int h = 0; h < 4; ++h) {
        float a0 = al[h * 32 + lr], a1 = al[h * 32 + 16 + lr];
        float r0 = ar[h * 32 + lr], r1 = ar[h * 32 + 16 + lr];
#pragma unroll
        for (int reg = 0; reg < 4; ++reg) {
            pel[reg][h] = acc[2 * h][reg] * a0 + acc[2 * h + 1][reg] * a1;
            per_[reg][h] = acc[2 * h][reg] * r0 + acc[2 * h + 1][reg] * r1;
        }
    }
#pragma unroll
    for (int off = 1; off < 16; off <<= 1) {
#pragma unroll
        for (int reg = 0; reg < 4; ++reg)
#pragma unroll
            for (int h = 0; h < 4; ++h) {
                pel[reg][h] += __shfl_xor(pel[reg][h], off);
                per_[reg][h] += __shfl_xor(per_[reg][h], off);
            }
    }
    if (lr == 0) {
#pragma unroll
        for (int reg = 0; reg < 4; ++reg) {
            int orow = rowbase + lg * 4 + reg;
            if (orow < n) {
#pragma unroll
                for (int h = 0; h < 4; ++h) {
                    el[orow * HH + h] = pel[reg][h];
                    er[orow * HH + h] = per_[reg][h];
                }
            }
        }
    }
}

// ============================ MFMA block-diag GEMM + relu + global max pool ============================
__global__ __launch_bounds__(256) void mfma_bd_pool(const float* __restrict__ agg,
                                                    const bf16x8* __restrict__ WFH,
                                                    const bf16x8* __restrict__ WFL,
                                                    unsigned* __restrict__ pooled, int n) {
    __shared__ float smax[4][128];
    const int tid = threadIdx.x;
    const int w = tid >> 6, l = tid & 63;
    const int lr = l & 15, lg = l >> 4;
    const int y = blockIdx.y;
    const int rowbase = blockIdx.x * 64 + w * 16;
    const int arow = rowbase + lr;
    const bf16x8* BH = WFH + (size_t)(64 + y * 32) * 64;
    const bf16x8* BL = WFL + (size_t)(64 + y * 32) * 64;

    f32x4 acc[8];
#pragma unroll
    for (int ct = 0; ct < 8; ++ct) acc[ct] = (f32x4){0.f, 0.f, 0.f, 0.f};

    for (int kt = 0; kt < 4; ++kt) {
        float a[8];
        if (arow < n) {
            float4 p0 = *reinterpret_cast<const float4*>(&agg[(size_t)arow * 512 + y * 128 + kt * 32 + lg * 8]);
            float4 p1 = *reinterpret_cast<const float4*>(&agg[(size_t)arow * 512 + y * 128 + kt * 32 + lg * 8 + 4]);
            a[0] = p0.x; a[1] = p0.y; a[2] = p0.z; a[3] = p0.w;
            a[4] = p1.x; a[5] = p1.y; a[6] = p1.z; a[7] = p1.w;
        } else {
#pragma unroll
            for (int j = 0; j < 8; ++j) a[j] = 0.f;
        }
        bf16x8 ah, alo;
#pragma unroll
        for (int j = 0; j < 8; ++j) {
            unsigned short hb = f2bf(a[j]);
            ah[j] = (short)hb;
            alo[j] = (short)f2bf(a[j] - bf2f(hb));
        }
        const bf16x8* bh = &BH[(size_t)(kt * 8) * 64 + l];
        const bf16x8* bl = &BL[(size_t)(kt * 8) * 64 + l];
#pragma unroll
        for (int ct = 0; ct < 8; ++ct) {
            bf16x8 b1 = bh[ct * 64];
            bf16x8 b2 = bl[ct * 64];
            acc[ct] = __builtin_amdgcn_mfma_f32_16x16x32_bf16(ah, b1, acc[ct], 0, 0, 0);
            acc[ct] = __builtin_amdgcn_mfma_f32_16x16x32_bf16(alo, b1, acc[ct], 0, 0, 0);
            acc[ct] = __builtin_amdgcn_mfma_f32_16x16x32_bf16(ah, b2, acc[ct], 0, 0, 0);
        }
    }
    float cm[8];
#pragma unroll
    for (int ct = 0; ct < 8; ++ct) {
        float v = fmaxf(fmaxf(acc[ct][0], acc[ct][1]), fmaxf(acc[ct][2], acc[ct][3]));
        cm[ct] = fmaxf(v, 0.f);
    }
#pragma unroll
    for (int ct = 0; ct < 8; ++ct) {
        cm[ct] = fmaxf(cm[ct], __shfl_xor(cm[ct], 16));
        cm[ct] = fmaxf(cm[ct], __shfl_xor(cm[ct], 32));
    }
    if (l < 16) {
#pragma unroll
        for (int ct = 0; ct < 8; ++ct) smax[w][ct * 16 + lr] = cm[ct];
    }
    __syncthreads();
    if (tid < 128) {
        float mx = fmaxf(fmaxf(smax[0][tid], smax[1][tid]), fmaxf(smax[2][tid], smax[3][tid]));
        atomicMax(&pooled[y * 128 + tid], __float_as_uint(mx));  // nonneg: uint order == float order
    }
}

// ============================ single-sweep softmax-gather (K=128) ============================
// Unnormalized accumulate with w=exp(lrelu(score)); z accumulated in-sweep; scale at end.
// 32 lanes cover the 128-col row (float4); two edges per iteration (lane halves).
// Output stored RELU'd. FUSE_ELR: also emit el2/er2 = out . wl/wr_h.
template <int FUSE_ELR>
__global__ __launch_bounds__(256) void aggr_wave128(const int* __restrict__ rs,
                                                    const int* __restrict__ csrc,
                                                    const float* __restrict__ el,
                                                    const float* __restrict__ er,
                                                    const float* __restrict__ f,
                                                    float* __restrict__ out,
                                                    const float* __restrict__ wl,
                                                    const float* __restrict__ wr,
                                                    float* __restrict__ el2,
                                                    float* __restrict__ er2, int n) {
    const int d = blockIdx.x * 4 + (threadIdx.x >> 6);
    if (d >= n) return;
    const int lane = threadIdx.x & 63;
    const int hg = lane >> 4, j16 = lane & 15;
    const int hw = lane >> 5;
    const int L31 = lane & 31;
    const int cb4 = L31 * 4;
    const int myh = L31 >> 3;  // head owning my 4 cols
    const int e0 = rs[d], e1 = rs[d + 1];
    const float erd = er[d * HH + hg];

    float4 acc = {0.f, 0.f, 0.f, 0.f};
    float zacc = 0.f;
    for (int c0 = e0; c0 < e1; c0 += 16) {
        const int cnt = min(16, e1 - c0);
        int s_mine = 0;
        float wmine = 0.f;
        if (j16 < cnt) {
            s_mine = csrc[c0 + j16];
            wmine = __expf(lrelu(el[s_mine * HH + hg] + erd));
        }
        zacc += wmine;
        const int pairs = cnt >> 1;
#pragma unroll 4
        for (int jj = 0; jj < pairs; ++jj) {
            int idx = 2 * jj + hw;
            int s = __shfl(s_mine, idx);
            float wv = __shfl(wmine, myh * 16 + idx);
            float4 xv = *reinterpret_cast<const float4*>(&f[(size_t)s * 128 + cb4]);
            acc.x = fmaf(wv, xv.x, acc.x);
            acc.y = fmaf(wv, xv.y, acc.y);
            acc.z = fmaf(wv, xv.z, acc.z);
            acc.w = fmaf(wv, xv.w, acc.w);
        }
        if (cnt & 1) {
            int idx = cnt - 1;
            int s = __shfl(s_mine, idx);
            float wv = hw ? 0.f : __shfl(wmine, myh * 16 + idx);
            float4 xv = *reinterpret_cast<const float4*>(&f[(size_t)s * 128 + cb4]);
            acc.x = fmaf(wv, xv.x, acc.x);
            acc.y = fmaf(wv, xv.y, acc.y);
            acc.z = fmaf(wv, xv.z, acc.z);
            acc.w = fmaf(wv, xv.w, acc.w);
        }
    }
    // z per head (reduce within 16-lane group), then pick my head's z
    float zh = zacc;
#pragma unroll
    for (int off = 1; off < 16; off <<= 1) zh += __shfl_xor(zh, off);
    float zmy = __shfl(zh, myh * 16);
    const float rz = (zmy > 0.f) ? 1.0f / zmy : 0.f;
    // cross-half reduce (both halves end identical)
    acc.x += __shfl_xor(acc.x, 32);
    acc.y += __shfl_xor(acc.y, 32);
    acc.z += __shfl_xor(acc.z, 32);
    acc.w += __shfl_xor(acc.w, 32);
    acc.x = fmaxf(acc.x * rz, 0.f);  // scale + relu (stored activated)
    acc.y = fmaxf(acc.y * rz, 0.f);
    acc.z = fmaxf(acc.z * rz, 0.f);
    acc.w = fmaxf(acc.w * rz, 0.f);
    if (hw == 0) *reinterpret_cast<float4*>(&out[(size_t)d * 128 + cb4]) = acc;
    if (FUSE_ELR) {
        float pl[4], pr[4];
#pragma unroll
        for (int h = 0; h < 4; ++h) {
            float4 wlv = *reinterpret_cast<const float4*>(&wl[h * 128 + cb4]);
            float4 wrv = *reinterpret_cast<const float4*>(&wr[h * 128 + cb4]);
            pl[h] = acc.x * wlv.x + acc.y * wlv.y + acc.z * wlv.z + acc.w * wlv.w;
            pr[h] = acc.x * wrv.x + acc.y * wrv.y + acc.z * wrv.z + acc.w * wrv.w;
        }
#pragma unroll
        for (int off = 1; off < 32; off <<= 1) {
#pragma unroll
            for (int h = 0; h < 4; ++h) {
                pl[h] += __shfl_xor(pl[h], off);
                pr[h] += __shfl_xor(pr[h], off);
            }
        }
        if (lane == 0) {
#pragma unroll
            for (int h = 0; h < 4; ++h) {
                el2[d * HH + h] = pl[h];
                er2[d * HH + h] = pr[h];
            }
        }
    }
}

// ============================ layer 2: wl/wr = W2_h @ al2_h ============================
__global__ void prep_wlr(const float* __restrict__ W2, const float* __restrict__ al2,
                         const float* __restrict__ ar2, float* __restrict__ wl,
                         float* __restrict__ wr) {
    int idx = blockIdx.x * blockDim.x + threadIdx.x;
    if (idx >= 512) return;
    int h = idx >> 7, i = idx & 127;
    float sl = 0.0f, sr = 0.0f;
    for (int c = 0; c < 128; ++c) {
        float w = W2[(size_t)i * 512 + h * 128 + c];
        sl = fmaf(w, al2[h * 128 + c], sl);
        sr = fmaf(w, ar2[h * 128 + c], sr);
    }
    wl[idx] = sl;
    wr[idx] = sr;
}

// ============================ layer 2: single-sweep aggregate of x rows, 4 per-head alphas ============================
// x (=B1) is stored already relu'd.
__global__ __launch_bounds__(256) void aggr_x(const int* __restrict__ rs,
                                              const int* __restrict__ csrc,
                                              const float* __restrict__ el,
                                              const float* __restrict__ er,
                                              const float* __restrict__ x,
                                              float* __restrict__ agg, int n) {
    const int d = blockIdx.x * 4 + (threadIdx.x >> 6);
    if (d >= n) return;
    const int lane = threadIdx.x & 63;
    const int hg = lane >> 4, j16 = lane & 15;
    const int hw = lane >> 5;
    const int L31 = lane & 31;
    const int cb4 = L31 * 4;
    const int e0 = rs[d], e1 = rs[d + 1];
    const float erd = er[d * HH + hg];

    float4 acc[4];
#pragma unroll
    for (int h = 0; h < 4; ++h) acc[h] = (float4){0.f, 0.f, 0.f, 0.f};
    float zacc = 0.f;
    for (int c0 = e0; c0 < e1; c0 += 16) {
        const int cnt = min(16, e1 - c0);
        int s_mine = 0;
        float wmine = 0.f;
        if (j16 < cnt) {
            s_mine = csrc[c0 + j16];
            wmine = __expf(lrelu(el[s_mine * HH + hg] + erd));
        }
        zacc += wmine;
        const int pairs = cnt >> 1;
#pragma unroll 2
        for (int jj = 0; jj < pairs; ++jj) {
            int idx = 2 * jj + hw;
            int s = __shfl(s_mine, idx);
            float w0 = __shfl(wmine, idx);
            float w1 = __shfl(wmine, 16 + idx);
            float w2 = __shfl(wmine, 32 + idx);
            float w3 = __shfl(wmine, 48 + idx);
            float4 xv = *reinterpret_cast<const float4*>(&x[(size_t)s * 128 + cb4]);
            acc[0].x = fmaf(w0, xv.x, acc[0].x); acc[0].y = fmaf(w0, xv.y, acc[0].y);
            acc[0].z = fmaf(w0, xv.z, acc[0].z); acc[0].w = fmaf(w0, xv.w, acc[0].w);
            acc[1].x = fmaf(w1, xv.x, acc[1].x); acc[1].y = fmaf(w1, xv.y, acc[1].y);
            acc[1].z = fmaf(w1, xv.z, acc[1].z); acc[1].w = fmaf(w1, xv.w, acc[1].w);
            acc[2].x = fmaf(w2, xv.x, acc[2].x); acc[2].y = fmaf(w2, xv.y, acc[2].y);
            acc[2].z = fmaf(w2, xv.z, acc[2].z); acc[2].w = fmaf(w2, xv.w, acc[2].w);
            acc[3].x = fmaf(w3, xv.x, acc[3].x); acc[3].y = fmaf(w3, xv.y, acc[3].y);
            acc[3].z = fmaf(w3, xv.z, acc[3].z); acc[3].w = fmaf(w3, xv.w, acc[3].w);
        }
        if (cnt & 1) {
            int idx = cnt - 1;
            int s = __shfl(s_mine, idx);
            float m = hw ? 0.f : 1.f;
            float w0 = m * __shfl(wmine, idx);
            float w1 = m * __shfl(wmine, 16 + idx);
            float w2 = m * __shfl(wmine, 32 + idx);
            float w3 = m * __shfl(wmine, 48 + idx);
            float4 xv = *reinterpret_cast<const float4*>(&x[(size_t)s * 128 + cb4]);
            acc[0].x = fmaf(w0, xv.x, acc[0].x); acc[0].y = fmaf(w0, xv.y, acc[0].y);
            acc[0].z = fmaf(w0, xv.z, acc[0].z); acc[0].w = fmaf(w0, xv.w, acc[0].w);
            acc[1].x = fmaf(w1, xv.x, acc[1].x); acc[1].y = fmaf(w1, xv.y, acc[1].y);
            acc[1].z = fmaf(w1, xv.z, acc[1].z); acc[1].w = fmaf(w1, xv.w, acc[1].w);
            acc[2].x = fmaf(w2, xv.x, acc[2].x); acc[2].y = fmaf(w2, xv.y, acc[2].y);
            acc[2].z = fmaf(w2, xv.z, acc[2].z); acc[2].w = fmaf(w2, xv.w, acc[2].w);
            acc[3].x = fmaf(w3, xv.x, acc[3].x); acc[3].y = fmaf(w3, xv.y, acc[3].y);
            acc[3].z = fmaf(w3, xv.z, acc[3].z); acc[3].w = fmaf(w3, xv.w, acc[3].w);
        }
    }
    // per-head z
    float zh = zacc;
#pragma unroll
    for (int off = 1; off < 16; off <<= 1) zh += __shfl_xor(zh, off);
    float rzh[4];
#pragma unroll
    for (int h = 0; h < 4; ++h) {
        float zv = __shfl(zh, h * 16);
        rzh[h] = (zv > 0.f) ? 1.0f / zv : 0.f;
    }
    // cross-half reduce + scale + store
#pragma unroll
    for (int h = 0; h < 4; ++h) {
        acc[h].x += __shfl_xor(acc[h].x, 32);
        acc[h].y += __shfl_xor(acc[h].y, 32);
        acc[h].z += __shfl_xor(acc[h].z, 32);
        acc[h].w += __shfl_xor(acc[h].w, 32);
        acc[h].x *= rzh[h]; acc[h].y *= rzh[h]; acc[h].z *= rzh[h]; acc[h].w *= rzh[h];
    }
    if (hw == 0) {
#pragma unroll
        for (int h = 0; h < 4; ++h)
            *reinterpret_cast<float4*>(&agg[(size_t)d * 512 + h * 128 + cb4]) = acc[h];
    }
}

// ============================ FC head + softmax ============================
__global__ void head_kernel(const float* __restrict__ pooled, const float* __restrict__ fcw,
                            const float* __restrict__ fcb, float* __restrict__ out) {
    __shared__ float logits[8];
    int t = threadIdx.x;
    if (t < 8) {
        float acc = fcb[t];
        for (int i = 0; i < 512; ++i) acc = fmaf(pooled[i], fcw[i * 8 + t], acc);
        logits[t] = acc;
    }
    __syncthreads();
    if (t == 0) {
        float mx = -1e30f;
        for (int j = 0; j < 8; ++j) mx = fmaxf(mx, logits[j]);
        float ex[8], s = 0.0f;
        for (int j = 0; j < 8; ++j) { ex[j] = expf(logits[j] - mx); s += ex[j]; }
        for (int j = 0; j < 8; ++j) out[j] = ex[j] / s;
    }
}

extern "C" void kernel_launch(void* const* d_in, const int* in_sizes, int n_in,
                              void* d_out, int out_size, void* d_ws, size_t ws_size,
                              hipStream_t stream) {
    const float* x0  = (const float*)d_in[0];
    const int*   src = (const int*)d_in[1];
    const int*   dst = (const int*)d_in[2];
    const float* W0  = (const float*)d_in[3];
    const float* al0 = (const float*)d_in[4];
    const float* ar0 = (const float*)d_in[5];
    const float* W1  = (const float*)d_in[6];
    const float* al1 = (const float*)d_in[7];
    const float* ar1 = (const float*)d_in[8];
    const float* W2  = (const float*)d_in[9];
    const float* al2 = (const float*)d_in[10];
    const float* ar2 = (const float*)d_in[11];
    const float* fcw = (const float*)d_in[12];
    const float* fcb = (const float*)d_in[13];
    float* outp = (float*)d_out;

    const int N = in_sizes[0] / 128;
    const int E = in_sizes[1];

    // -------- workspace layout (floats) --------
    float* F    = (float*)d_ws;                  // N*128
    float* B0   = F + (size_t)N * 128;           // N*128 (relu'd)
    float* B1   = B0 + (size_t)N * 128;          // N*128 (relu'd)
    float* AGG  = B1 + (size_t)N * 128;          // N*512
    float* el   = AGG + (size_t)N * 512;         // N*4
    float* er   = el + (size_t)N * HH;           // N*4
    float* el2  = er + (size_t)N * HH;           // N*4
    float* er2  = el2 + (size_t)N * HH;          // N*4
    float* wl   = er2 + (size_t)N * HH;          // 512
    float* wr   = wl + 512;                      // 512
    float* pooled = wr + 512;                    // 512
    int* rs   = (int*)(pooled + 512);            // N+1
    int* deg  = rs + (N + 1);                    // N
    int* cur  = deg + N;                         // N
    int* bsum = cur + N;                         // 64
    int* csrc = bsum + 64;                       // E
    uintptr_t wfaddr = ((uintptr_t)(csrc + E) + 15) & ~(uintptr_t)15;
    bf16x8* WFH = (bf16x8*)wfaddr;               // 192*64 frags * 16 B
    bf16x8* WFL = WFH + (size_t)192 * 64;

    // -------- CSR build + W prepack --------
    hipMemsetAsync(deg, 0, (size_t)2 * N * sizeof(int), stream);
    hipMemsetAsync(pooled, 0, 512 * sizeof(float), stream);
    prep_wfrag<<<48, 256, 0, stream>>>(W0, W1, W2, WFH, WFL);
    prep_wlr<<<2, 256, 0, stream>>>(W2, al2, ar2, wl, wr);
    hist_kernel<<<(E + 255) / 256, 256, 0, stream>>>(dst, deg, E);
    const int nb = (N + 1023) / 1024;
    scan_block<<<nb, 1024, 0, stream>>>(deg, rs, bsum, N);
    scan_top<<<1, 64, 0, stream>>>(bsum, nb);
    scan_add<<<(N + 255) / 256, 256, 0, stream>>>(rs, bsum, N);
    scatter_kernel<<<(E + 255) / 256, 256, 0, stream>>>(src, dst, rs, cur, csrc, E);

    const int rowTiles = (N + 63) / 64;
    const int nodeBlocks = (N + 3) / 4;

    // -------- layer 0 --------
    mfma_gemm128<<<rowTiles, 256, 0, stream>>>(x0, WFH, WFL, F, al0, ar0, el, er, N);
    aggr_wave128<0><<<nodeBlocks, 256, 0, stream>>>(rs, csrc, el, er, F, B0,
                                                    nullptr, nullptr, nullptr, nullptr, N);
    // -------- layer 1 (aggr fuses el2/er2) --------
    mfma_gemm128<<<rowTiles, 256, 0, stream>>>(B0, WFH + (size_t)32 * 64, WFL + (size_t)32 * 64,
                                               F, al1, ar1, el, er, N);
    aggr_wave128<1><<<nodeBlocks, 256, 0, stream>>>(rs, csrc, el, er, F, B1,
                                                    wl, wr, el2, er2, N);
    // -------- layer 2 (aggregate-then-project) --------
    aggr_x<<<nodeBlocks, 256, 0, stream>>>(rs, csrc, el2, er2, B1, AGG, N);
    mfma_bd_pool<<<dim3(rowTiles, 4), 256, 0, stream>>>(AGG, WFH, WFL, (unsigned*)pooled, N);

    head_kernel<<<1, 64, 0, stream>>>(pooled, fcw, fcb, outp);
}